// Round 1
// baseline (1704.484 us; speedup 1.0000x reference)
//
#include <hip/hip_runtime.h>
#include <math.h>

#define DD 128

__device__ __forceinline__ float4 f4zero() { return make_float4(0.f, 0.f, 0.f, 0.f); }
__device__ __forceinline__ void fma4(float4& a, float s, const float4& w) {
    a.x = fmaf(s, w.x, a.x);
    a.y = fmaf(s, w.y, a.y);
    a.z = fmaf(s, w.z, a.z);
    a.w = fmaf(s, w.w, a.w);
}

// ---------------------------------------------------------------------------
// Kernel 1: compose weights.
//   Wqp  = Wq @ We1            [128,128]
//   Wkp  = Wk @ We1            [128,128]
//   Wp2e = Wp2 @ We1           [3,128]
//   bKP  = bp2 @ We1 + be1     [128]
// grid 128 blocks x 128 threads; block i computes row i.
// ---------------------------------------------------------------------------
__global__ __launch_bounds__(128) void compose_weights(
    const float* __restrict__ Wq, const float* __restrict__ Wk,
    const float* __restrict__ We1, const float* __restrict__ Wp2,
    const float* __restrict__ bp2, const float* __restrict__ be1,
    float* __restrict__ Wqp, float* __restrict__ Wkp,
    float* __restrict__ Wp2e, float* __restrict__ bKP) {
    int i = blockIdx.x;
    int j = threadIdx.x;
    float aq = 0.f, ak = 0.f;
    for (int k = 0; k < DD; ++k) {
        float w = We1[k * DD + j];
        aq = fmaf(Wq[i * DD + k], w, aq);
        ak = fmaf(Wk[i * DD + k], w, ak);
    }
    Wqp[i * DD + j] = aq;
    Wkp[i * DD + j] = ak;
    if (i < 3) {
        float a = 0.f;
        for (int k = 0; k < DD; ++k) a = fmaf(Wp2[i * DD + k], We1[k * DD + j], a);
        Wp2e[i * DD + j] = a;
    }
    if (i == 3) {
        float a = be1[j];
        for (int k = 0; k < DD; ++k) a = fmaf(bp2[k], We1[k * DD + j], a);
        bKP[j] = a;
    }
}

// ---------------------------------------------------------------------------
// Kernel 2: node projections (fused 3x GEMM + tiny position MLP).
//   QW[n]  = h[n] @ Wqp                          -> QW  [N][128]
//   KPW[n] = h[n] @ Wkp + u[n] @ Wp2e + bKP       \
//   VP[n]  = h[n] @ Wv  + u[n] @ Wp2  + bp2       -> SP [N][256] interleaved
//   (SP[n][2j] = KPW[n][j], SP[n][2j+1] = VP[n][j])
//   u[n] = relu(c[n] @ Wp1 + bp1)   [3]
// 64 rows per block, 256 threads: cg = t&31 (4 cols), rg = t>>5 (8 rows).
// ---------------------------------------------------------------------------
__global__ __launch_bounds__(256) void node_proj(
    const float* __restrict__ h, const float* __restrict__ c,
    const float* __restrict__ Wqp, const float* __restrict__ Wkp,
    const float* __restrict__ Wv, const float* __restrict__ Wp1,
    const float* __restrict__ bp1, const float* __restrict__ Wp2,
    const float* __restrict__ bp2, const float* __restrict__ Wp2e,
    const float* __restrict__ bKP,
    float* __restrict__ QW, float* __restrict__ SP, int N) {
    __shared__ float h_lds[64 * DD];
    __shared__ float u_lds[64 * 4];

    const int row0 = blockIdx.x * 64;
    const int t = threadIdx.x;

    // stage h tile (64 rows x 128 cols) as float4
#pragma unroll
    for (int i = 0; i < 8; ++i) {
        int f = t + i * 256;      // float4 slot id within 2048
        int row = f >> 5;
        int cq = f & 31;
        float4 v = f4zero();
        if (row0 + row < N) v = *(const float4*)&h[(size_t)(row0 + row) * DD + cq * 4];
        *(float4*)&h_lds[row * DD + cq * 4] = v;
    }
    // u = relu(c @ Wp1 + bp1), 3 per row
    if (t < 192) {
        int row = t / 3;
        int i = t - row * 3;
        float u = 0.f;
        if (row0 + row < N) {
            const float* cr = &c[(size_t)(row0 + row) * 3];
            u = bp1[i];
            u = fmaf(cr[0], Wp1[0 * 3 + i], u);
            u = fmaf(cr[1], Wp1[1 * 3 + i], u);
            u = fmaf(cr[2], Wp1[2 * 3 + i], u);
            u = fmaxf(u, 0.f);
        }
        u_lds[row * 4 + i] = u;
    }
    __syncthreads();

    const int cg = t & 31;
    const int rg = t >> 5;

    float4 aq[8], ak[8], av[8];
#pragma unroll
    for (int r = 0; r < 8; ++r) { aq[r] = f4zero(); ak[r] = f4zero(); av[r] = f4zero(); }

    for (int k = 0; k < DD; ++k) {
        float4 wq = *(const float4*)&Wqp[k * DD + cg * 4];
        float4 wk = *(const float4*)&Wkp[k * DD + cg * 4];
        float4 wv = *(const float4*)&Wv[k * DD + cg * 4];
#pragma unroll
        for (int r = 0; r < 8; ++r) {
            float hv = h_lds[(rg * 8 + r) * DD + k];
            fma4(aq[r], hv, wq);
            fma4(ak[r], hv, wk);
            fma4(av[r], hv, wv);
        }
    }

    // epilogue: position-MLP contributions + biases, interleaved store
    float4 e0 = *(const float4*)&Wp2e[0 * DD + cg * 4];
    float4 e1 = *(const float4*)&Wp2e[1 * DD + cg * 4];
    float4 e2 = *(const float4*)&Wp2e[2 * DD + cg * 4];
    float4 p0 = *(const float4*)&Wp2[0 * DD + cg * 4];
    float4 p1 = *(const float4*)&Wp2[1 * DD + cg * 4];
    float4 p2 = *(const float4*)&Wp2[2 * DD + cg * 4];
    float4 bk = *(const float4*)&bKP[cg * 4];
    float4 bp = *(const float4*)&bp2[cg * 4];

#pragma unroll
    for (int r = 0; r < 8; ++r) {
        int row = rg * 8 + r;
        if (row0 + row >= N) continue;
        float u0 = u_lds[row * 4 + 0];
        float u1 = u_lds[row * 4 + 1];
        float u2 = u_lds[row * 4 + 2];

        float4 K = ak[r];
        fma4(K, u0, e0); fma4(K, u1, e1); fma4(K, u2, e2);
        K.x += bk.x; K.y += bk.y; K.z += bk.z; K.w += bk.w;

        float4 V = av[r];
        fma4(V, u0, p0); fma4(V, u1, p1); fma4(V, u2, p2);
        V.x += bp.x; V.y += bp.y; V.z += bp.z; V.w += bp.w;

        *(float4*)&QW[(size_t)(row0 + row) * DD + cg * 4] = aq[r];

        float4 s0 = make_float4(K.x, V.x, K.y, V.y);
        float4 s1 = make_float4(K.z, V.z, K.w, V.w);
        float* sp = &SP[(size_t)(row0 + row) * 2 * DD + cg * 8];
        *(float4*)&sp[0] = s0;
        *(float4*)&sp[4] = s1;
    }
}

// ---------------------------------------------------------------------------
// Kernel 3: per-edge score + scatter. One wave (64 lanes) per edge.
//   t     = relu(KPW[src] - QW[dst])      [128]
//   raw   = t @ We2 + be2
//   score = exp(clip(raw / sqrt(128), -5, 5))
//   wV[dst] += score * VP[src];  z[dst] += score
// ---------------------------------------------------------------------------
__global__ __launch_bounds__(256) void edge_kernel(
    const int* __restrict__ src, const int* __restrict__ dst,
    const float* __restrict__ SP, const float* __restrict__ QW,
    const float* __restrict__ We2, const float* __restrict__ be2,
    float* __restrict__ wV, float* __restrict__ z, int E) {
    int wid = (blockIdx.x * 256 + threadIdx.x) >> 6;
    int lane = threadIdx.x & 63;
    if (wid >= E) return;

    int s = src[wid];
    int d = dst[wid];

    // SP row: k0,v0,k1,v1 per lane (float4)
    float4 a = *(const float4*)&SP[(size_t)s * 256 + lane * 4];
    float2 q = *(const float2*)&QW[(size_t)d * DD + lane * 2];
    float t0 = fmaxf(a.x - q.x, 0.f);
    float t1 = fmaxf(a.z - q.y, 0.f);
    float2 w2 = *(const float2*)&We2[lane * 2];
    float p = fmaf(t0, w2.x, t1 * w2.y);

#pragma unroll
    for (int off = 32; off > 0; off >>= 1) p += __shfl_xor(p, off);

    float raw = (p + be2[0]) * 0.08838834764831845f;  // 1/sqrt(128)
    raw = fminf(fmaxf(raw, -5.f), 5.f);
    float score = expf(raw);

    atomicAdd(&wV[(size_t)d * DD + lane * 2 + 0], a.y * score);
    atomicAdd(&wV[(size_t)d * DD + lane * 2 + 1], a.w * score);
    if (lane == 0) atomicAdd(&z[d], score);
}

// ---------------------------------------------------------------------------
// Kernel 4: out = (wV / z) @ Wo + bo
// ---------------------------------------------------------------------------
__global__ __launch_bounds__(256) void out_proj(
    const float* __restrict__ wV, const float* __restrict__ z,
    const float* __restrict__ Wo, const float* __restrict__ bo,
    float* __restrict__ out, int N) {
    __shared__ float a_lds[64 * DD];
    const int row0 = blockIdx.x * 64;
    const int t = threadIdx.x;

#pragma unroll
    for (int i = 0; i < 8; ++i) {
        int f = t + i * 256;
        int row = f >> 5;
        int cq = f & 31;
        float4 v = f4zero();
        if (row0 + row < N) {
            v = *(const float4*)&wV[(size_t)(row0 + row) * DD + cq * 4];
            float rz = 1.0f / z[row0 + row];
            v.x *= rz; v.y *= rz; v.z *= rz; v.w *= rz;
        }
        *(float4*)&a_lds[row * DD + cq * 4] = v;
    }
    __syncthreads();

    const int cg = t & 31;
    const int rg = t >> 5;
    float4 acc[8];
#pragma unroll
    for (int r = 0; r < 8; ++r) acc[r] = f4zero();

    for (int k = 0; k < DD; ++k) {
        float4 wo = *(const float4*)&Wo[k * DD + cg * 4];
#pragma unroll
        for (int r = 0; r < 8; ++r) {
            float hv = a_lds[(rg * 8 + r) * DD + k];
            fma4(acc[r], hv, wo);
        }
    }

    float4 b = *(const float4*)&bo[cg * 4];
#pragma unroll
    for (int r = 0; r < 8; ++r) {
        int row = rg * 8 + r;
        if (row0 + row >= N) continue;
        float4 o = acc[r];
        o.x += b.x; o.y += b.y; o.z += b.z; o.w += b.w;
        *(float4*)&out[(size_t)(row0 + row) * DD + cg * 4] = o;
    }
}

// ---------------------------------------------------------------------------
extern "C" void kernel_launch(void* const* d_in, const int* in_sizes, int n_in,
                              void* d_out, int out_size, void* d_ws, size_t ws_size,
                              hipStream_t stream) {
    const float* h   = (const float*)d_in[0];
    const float* c   = (const float*)d_in[1];
    const int*   src = (const int*)d_in[2];
    const int*   dst = (const int*)d_in[3];
    const float* Wq  = (const float*)d_in[4];
    const float* Wk  = (const float*)d_in[5];
    const float* Wv  = (const float*)d_in[6];
    const float* Wp1 = (const float*)d_in[7];
    const float* bp1 = (const float*)d_in[8];
    const float* Wp2 = (const float*)d_in[9];
    const float* bp2 = (const float*)d_in[10];
    const float* We1 = (const float*)d_in[11];
    const float* be1 = (const float*)d_in[12];
    const float* We2 = (const float*)d_in[13];
    const float* be2 = (const float*)d_in[14];
    const float* Wo  = (const float*)d_in[15];
    const float* bo  = (const float*)d_in[16];

    const int N = in_sizes[0] / DD;
    const int E = in_sizes[2];

    float* ws   = (float*)d_ws;
    float* Wqp  = ws;                       // 128*128
    float* Wkp  = Wqp + DD * DD;            // 128*128
    float* Wp2e = Wkp + DD * DD;            // 3*128
    float* bKP  = Wp2e + 3 * DD;            // 128
    float* QW   = bKP + DD;                 // N*128
    float* SP   = QW + (size_t)N * DD;      // N*256 (KPW/VP interleaved)
    float* wV   = SP + (size_t)N * 2 * DD;  // N*128
    float* zb   = wV + (size_t)N * DD;      // N

    // zero the accumulators (wV and z are contiguous)
    hipMemsetAsync(wV, 0, ((size_t)N * DD + N) * sizeof(float), stream);

    compose_weights<<<DD, DD, 0, stream>>>(Wq, Wk, We1, Wp2, bp2, be1,
                                           Wqp, Wkp, Wp2e, bKP);

    node_proj<<<(N + 63) / 64, 256, 0, stream>>>(h, c, Wqp, Wkp, Wv, Wp1, bp1,
                                                 Wp2, bp2, Wp2e, bKP, QW, SP, N);

    edge_kernel<<<(E + 3) / 4, 256, 0, stream>>>(src, dst, SP, QW, We2, be2,
                                                 wV, zb, E);

    out_proj<<<(N + 63) / 64, 256, 0, stream>>>(wV, zb, Wo, bo, (float*)d_out, N);
}

// Round 2
// 688.303 us; speedup vs baseline: 2.4764x; 2.4764x over previous
//
#include <hip/hip_runtime.h>
#include <math.h>

#define DD 128

__device__ __forceinline__ float4 f4zero() { return make_float4(0.f, 0.f, 0.f, 0.f); }
__device__ __forceinline__ void fma4(float4& a, float s, const float4& w) {
    a.x = fmaf(s, w.x, a.x);
    a.y = fmaf(s, w.y, a.y);
    a.z = fmaf(s, w.z, a.z);
    a.w = fmaf(s, w.w, a.w);
}

// ---------------------------------------------------------------------------
// Kernel 1: compose weights.
//   Wqp = Wq@We1, Wkp = Wk@We1, Wp2e = Wp2@We1, bKP = bp2@We1 + be1
// ---------------------------------------------------------------------------
__global__ __launch_bounds__(128) void compose_weights(
    const float* __restrict__ Wq, const float* __restrict__ Wk,
    const float* __restrict__ We1, const float* __restrict__ Wp2,
    const float* __restrict__ bp2, const float* __restrict__ be1,
    float* __restrict__ Wqp, float* __restrict__ Wkp,
    float* __restrict__ Wp2e, float* __restrict__ bKP) {
    int i = blockIdx.x;
    int j = threadIdx.x;
    float aq = 0.f, ak = 0.f;
    for (int k = 0; k < DD; ++k) {
        float w = We1[k * DD + j];
        aq = fmaf(Wq[i * DD + k], w, aq);
        ak = fmaf(Wk[i * DD + k], w, ak);
    }
    Wqp[i * DD + j] = aq;
    Wkp[i * DD + j] = ak;
    if (i < 3) {
        float a = 0.f;
        for (int k = 0; k < DD; ++k) a = fmaf(Wp2[i * DD + k], We1[k * DD + j], a);
        Wp2e[i * DD + j] = a;
    }
    if (i == 3) {
        float a = be1[j];
        for (int k = 0; k < DD; ++k) a = fmaf(bp2[k], We1[k * DD + j], a);
        bKP[j] = a;
    }
}

// ---------------------------------------------------------------------------
// Kernel 2: node projections (unchanged from R1).
//   QW[n] = h[n]@Wqp ; SP[n] interleaves KPW and VP (k0,v0,k1,v1,...)
// ---------------------------------------------------------------------------
__global__ __launch_bounds__(256) void node_proj(
    const float* __restrict__ h, const float* __restrict__ c,
    const float* __restrict__ Wqp, const float* __restrict__ Wkp,
    const float* __restrict__ Wv, const float* __restrict__ Wp1,
    const float* __restrict__ bp1, const float* __restrict__ Wp2,
    const float* __restrict__ bp2, const float* __restrict__ Wp2e,
    const float* __restrict__ bKP,
    float* __restrict__ QW, float* __restrict__ SP, int N) {
    __shared__ float h_lds[64 * DD];
    __shared__ float u_lds[64 * 4];

    const int row0 = blockIdx.x * 64;
    const int t = threadIdx.x;

#pragma unroll
    for (int i = 0; i < 8; ++i) {
        int f = t + i * 256;
        int row = f >> 5;
        int cq = f & 31;
        float4 v = f4zero();
        if (row0 + row < N) v = *(const float4*)&h[(size_t)(row0 + row) * DD + cq * 4];
        *(float4*)&h_lds[row * DD + cq * 4] = v;
    }
    if (t < 192) {
        int row = t / 3;
        int i = t - row * 3;
        float u = 0.f;
        if (row0 + row < N) {
            const float* cr = &c[(size_t)(row0 + row) * 3];
            u = bp1[i];
            u = fmaf(cr[0], Wp1[0 * 3 + i], u);
            u = fmaf(cr[1], Wp1[1 * 3 + i], u);
            u = fmaf(cr[2], Wp1[2 * 3 + i], u);
            u = fmaxf(u, 0.f);
        }
        u_lds[row * 4 + i] = u;
    }
    __syncthreads();

    const int cg = t & 31;
    const int rg = t >> 5;

    float4 aq[8], ak[8], av[8];
#pragma unroll
    for (int r = 0; r < 8; ++r) { aq[r] = f4zero(); ak[r] = f4zero(); av[r] = f4zero(); }

    for (int k = 0; k < DD; ++k) {
        float4 wq = *(const float4*)&Wqp[k * DD + cg * 4];
        float4 wk = *(const float4*)&Wkp[k * DD + cg * 4];
        float4 wv = *(const float4*)&Wv[k * DD + cg * 4];
#pragma unroll
        for (int r = 0; r < 8; ++r) {
            float hv = h_lds[(rg * 8 + r) * DD + k];
            fma4(aq[r], hv, wq);
            fma4(ak[r], hv, wk);
            fma4(av[r], hv, wv);
        }
    }

    float4 e0 = *(const float4*)&Wp2e[0 * DD + cg * 4];
    float4 e1 = *(const float4*)&Wp2e[1 * DD + cg * 4];
    float4 e2 = *(const float4*)&Wp2e[2 * DD + cg * 4];
    float4 p0 = *(const float4*)&Wp2[0 * DD + cg * 4];
    float4 p1 = *(const float4*)&Wp2[1 * DD + cg * 4];
    float4 p2 = *(const float4*)&Wp2[2 * DD + cg * 4];
    float4 bk = *(const float4*)&bKP[cg * 4];
    float4 bp = *(const float4*)&bp2[cg * 4];

#pragma unroll
    for (int r = 0; r < 8; ++r) {
        int row = rg * 8 + r;
        if (row0 + row >= N) continue;
        float u0 = u_lds[row * 4 + 0];
        float u1 = u_lds[row * 4 + 1];
        float u2 = u_lds[row * 4 + 2];

        float4 K = ak[r];
        fma4(K, u0, e0); fma4(K, u1, e1); fma4(K, u2, e2);
        K.x += bk.x; K.y += bk.y; K.z += bk.z; K.w += bk.w;

        float4 V = av[r];
        fma4(V, u0, p0); fma4(V, u1, p1); fma4(V, u2, p2);
        V.x += bp.x; V.y += bp.y; V.z += bp.z; V.w += bp.w;

        *(float4*)&QW[(size_t)(row0 + row) * DD + cg * 4] = aq[r];

        float4 s0 = make_float4(K.x, V.x, K.y, V.y);
        float4 s1 = make_float4(K.z, V.z, K.w, V.w);
        float* sp = &SP[(size_t)(row0 + row) * 2 * DD + cg * 8];
        *(float4*)&sp[0] = s0;
        *(float4*)&sp[4] = s1;
    }
}

// ---------------------------------------------------------------------------
// Counting sort of edges by dst -> CSR.
// ---------------------------------------------------------------------------
__global__ __launch_bounds__(256) void k_hist(const int* __restrict__ dst,
                                              int* __restrict__ deg, int E) {
    int i = blockIdx.x * 256 + threadIdx.x;
    int stride = gridDim.x * 256;
    for (; i < E; i += stride) atomicAdd(&deg[dst[i]], 1);
}

// per-block exclusive scan over 2048 elements (256 thr x 8), emits block total
__global__ __launch_bounds__(256) void k_scan1(const int* __restrict__ deg,
                                               int* __restrict__ offs,
                                               int* __restrict__ blockSums, int n) {
    __shared__ int ts[256];
    int b = blockIdx.x, t = threadIdx.x;
    int base = b * 2048 + t * 8;
    int v[8];
    int s = 0;
#pragma unroll
    for (int i = 0; i < 8; ++i) {
        int idx = base + i;
        v[i] = (idx < n) ? deg[idx] : 0;
        s += v[i];
    }
    ts[t] = s;
    __syncthreads();
    for (int off = 1; off < 256; off <<= 1) {
        int x = (t >= off) ? ts[t - off] : 0;
        __syncthreads();
        ts[t] += x;
        __syncthreads();
    }
    int run = ts[t] - s;  // exclusive prefix of this thread within block
    if (t == 255) blockSums[b] = ts[255];
#pragma unroll
    for (int i = 0; i < 8; ++i) {
        int idx = base + i;
        if (idx < n) offs[idx] = run;
        run += v[i];
    }
}

// single-block exclusive scan of block sums (nb <= 256)
__global__ __launch_bounds__(256) void k_scan2(int* __restrict__ bs, int nb) {
    __shared__ int s[256];
    int t = threadIdx.x;
    int orig = (t < nb) ? bs[t] : 0;
    s[t] = orig;
    __syncthreads();
    for (int off = 1; off < 256; off <<= 1) {
        int x = (t >= off) ? s[t - off] : 0;
        __syncthreads();
        s[t] += x;
        __syncthreads();
    }
    if (t < nb) bs[t] = s[t] - orig;
}

// add block offsets; also init cursor copy and the sentinel offs[n] = E
__global__ __launch_bounds__(256) void k_scan3(int* __restrict__ offs,
                                               int* __restrict__ cursor,
                                               const int* __restrict__ bs,
                                               int n, int E) {
    int b = blockIdx.x, t = threadIdx.x;
    int add = bs[b];
    int base = b * 2048 + t * 8;
#pragma unroll
    for (int i = 0; i < 8; ++i) {
        int idx = base + i;
        if (idx < n) {
            int o = offs[idx] + add;
            offs[idx] = o;
            cursor[idx] = o;
        }
    }
    if (b == gridDim.x - 1 && t == 255) offs[n] = E;
}

__global__ __launch_bounds__(256) void k_scatter(const int* __restrict__ src,
                                                 const int* __restrict__ dst,
                                                 int* __restrict__ cursor,
                                                 int* __restrict__ ssrc, int E) {
    int i = blockIdx.x * 256 + threadIdx.x;
    int stride = gridDim.x * 256;
    for (; i < E; i += stride) {
        int d = dst[i];
        int pos = atomicAdd(&cursor[d], 1);
        ssrc[pos] = src[i];
    }
}

// ---------------------------------------------------------------------------
// Kernel 3: CSR aggregate — one wave per dst node, register accumulation.
//   head[d] = sum_e score_e * VP[src_e] / sum_e score_e
// ---------------------------------------------------------------------------
__global__ __launch_bounds__(256) void aggregate(
    const int* __restrict__ offs, const int* __restrict__ ssrc,
    const float* __restrict__ SP, const float* __restrict__ QW,
    const float* __restrict__ We2, const float* __restrict__ be2,
    float* __restrict__ head, int N) {
    const int node = (blockIdx.x * 256 + threadIdx.x) >> 6;
    const int lane = threadIdx.x & 63;
    if (node >= N) return;

    const float INVS = 0.08838834764831845f;  // 1/sqrt(128)
    float2 q = *(const float2*)&QW[(size_t)node * DD + lane * 2];
    float2 w2 = *(const float2*)&We2[lane * 2];
    float b2 = be2[0];

    int beg = offs[node], end = offs[node + 1];
    float acc0 = 0.f, acc1 = 0.f, zacc = 0.f;

    int e = beg;
    for (; e + 1 < end; e += 2) {
        int s0 = ssrc[e];
        int s1 = ssrc[e + 1];
        float4 a0 = *(const float4*)&SP[(size_t)s0 * 256 + lane * 4];
        float4 a1 = *(const float4*)&SP[(size_t)s1 * 256 + lane * 4];
        float p0 = fmaf(fmaxf(a0.x - q.x, 0.f), w2.x, fmaxf(a0.z - q.y, 0.f) * w2.y);
        float p1 = fmaf(fmaxf(a1.x - q.x, 0.f), w2.x, fmaxf(a1.z - q.y, 0.f) * w2.y);
#pragma unroll
        for (int off = 32; off; off >>= 1) {
            p0 += __shfl_xor(p0, off);
            p1 += __shfl_xor(p1, off);
        }
        float sc0 = expf(fminf(fmaxf((p0 + b2) * INVS, -5.f), 5.f));
        float sc1 = expf(fminf(fmaxf((p1 + b2) * INVS, -5.f), 5.f));
        acc0 = fmaf(a0.y, sc0, acc0);
        acc1 = fmaf(a0.w, sc0, acc1);
        acc0 = fmaf(a1.y, sc1, acc0);
        acc1 = fmaf(a1.w, sc1, acc1);
        zacc += sc0 + sc1;
    }
    if (e < end) {
        int s0 = ssrc[e];
        float4 a0 = *(const float4*)&SP[(size_t)s0 * 256 + lane * 4];
        float p0 = fmaf(fmaxf(a0.x - q.x, 0.f), w2.x, fmaxf(a0.z - q.y, 0.f) * w2.y);
#pragma unroll
        for (int off = 32; off; off >>= 1) p0 += __shfl_xor(p0, off);
        float sc0 = expf(fminf(fmaxf((p0 + b2) * INVS, -5.f), 5.f));
        acc0 = fmaf(a0.y, sc0, acc0);
        acc1 = fmaf(a0.w, sc0, acc1);
        zacc += sc0;
    }

    float rz = 1.0f / zacc;
    float2 o = make_float2(acc0 * rz, acc1 * rz);
    *(float2*)&head[(size_t)node * DD + lane * 2] = o;
}

// ---------------------------------------------------------------------------
// Kernel 4: out = head @ Wo + bo, IN PLACE on d_out (head lives in d_out).
// Each block stages its own 64 rows in LDS before overwriting them.
// ---------------------------------------------------------------------------
__global__ __launch_bounds__(256) void out_proj(
    float* __restrict__ inout, const float* __restrict__ Wo,
    const float* __restrict__ bo, int N) {
    __shared__ float a_lds[64 * DD];
    const int row0 = blockIdx.x * 64;
    const int t = threadIdx.x;

#pragma unroll
    for (int i = 0; i < 8; ++i) {
        int f = t + i * 256;
        int row = f >> 5;
        int cq = f & 31;
        float4 v = f4zero();
        if (row0 + row < N) v = *(const float4*)&inout[(size_t)(row0 + row) * DD + cq * 4];
        *(float4*)&a_lds[row * DD + cq * 4] = v;
    }
    __syncthreads();

    const int cg = t & 31;
    const int rg = t >> 5;
    float4 acc[8];
#pragma unroll
    for (int r = 0; r < 8; ++r) acc[r] = f4zero();

    for (int k = 0; k < DD; ++k) {
        float4 wo = *(const float4*)&Wo[k * DD + cg * 4];
#pragma unroll
        for (int r = 0; r < 8; ++r) {
            float hv = a_lds[(rg * 8 + r) * DD + k];
            fma4(acc[r], hv, wo);
        }
    }

    float4 b = *(const float4*)&bo[cg * 4];
#pragma unroll
    for (int r = 0; r < 8; ++r) {
        int row = rg * 8 + r;
        if (row0 + row >= N) continue;
        float4 o = acc[r];
        o.x += b.x; o.y += b.y; o.z += b.z; o.w += b.w;
        *(float4*)&inout[(size_t)(row0 + row) * DD + cg * 4] = o;
    }
}

// ---------------------------------------------------------------------------
extern "C" void kernel_launch(void* const* d_in, const int* in_sizes, int n_in,
                              void* d_out, int out_size, void* d_ws, size_t ws_size,
                              hipStream_t stream) {
    const float* h   = (const float*)d_in[0];
    const float* c   = (const float*)d_in[1];
    const int*   src = (const int*)d_in[2];
    const int*   dst = (const int*)d_in[3];
    const float* Wq  = (const float*)d_in[4];
    const float* Wk  = (const float*)d_in[5];
    const float* Wv  = (const float*)d_in[6];
    const float* Wp1 = (const float*)d_in[7];
    const float* bp1 = (const float*)d_in[8];
    const float* Wp2 = (const float*)d_in[9];
    const float* bp2 = (const float*)d_in[10];
    const float* We1 = (const float*)d_in[11];
    const float* be1 = (const float*)d_in[12];
    const float* We2 = (const float*)d_in[13];
    const float* be2 = (const float*)d_in[14];
    const float* Wo  = (const float*)d_in[15];
    const float* bo  = (const float*)d_in[16];

    const int N = in_sizes[0] / DD;
    const int E = in_sizes[2];

    float* ws   = (float*)d_ws;
    float* Wqp  = ws;                      // 128*128
    float* Wkp  = Wqp + DD * DD;           // 128*128
    float* Wp2e = Wkp + DD * DD;           // 3*128
    float* bKP  = Wp2e + 3 * DD;           // 128
    float* QW   = bKP + DD;                // N*128
    float* SP   = QW + (size_t)N * DD;     // N*256 (KPW/VP interleaved)
    int*   offs   = (int*)(SP + (size_t)N * 2 * DD);  // N+1
    int*   cursor = offs + (N + 1);                    // N+1 (also deg)
    int*   bsums  = cursor + (N + 1);                  // 64
    int*   ssrc   = bsums + 64;                        // E

    float* head = (float*)d_out;  // head_out written in place, then out_proj in place

    const int NB = (N + 2047) / 2048;

    // deg (= cursor array) zeroed for histogram
    hipMemsetAsync(cursor, 0, (size_t)(N + 1) * sizeof(int), stream);

    compose_weights<<<DD, DD, 0, stream>>>(Wq, Wk, We1, Wp2, bp2, be1,
                                           Wqp, Wkp, Wp2e, bKP);

    node_proj<<<(N + 63) / 64, 256, 0, stream>>>(h, c, Wqp, Wkp, Wv, Wp1, bp1,
                                                 Wp2, bp2, Wp2e, bKP, QW, SP, N);

    // CSR build: hist into cursor, scan into offs, scatter src ids
    k_hist<<<2048, 256, 0, stream>>>(dst, cursor, E);
    k_scan1<<<NB, 256, 0, stream>>>(cursor, offs, bsums, N);
    k_scan2<<<1, 256, 0, stream>>>(bsums, NB);
    k_scan3<<<NB, 256, 0, stream>>>(offs, cursor, bsums, N, E);
    k_scatter<<<2048, 256, 0, stream>>>(src, dst, cursor, ssrc, E);

    aggregate<<<(N * 64 + 255) / 256, 256, 0, stream>>>(offs, ssrc, SP, QW,
                                                        We2, be2, head, N);

    out_proj<<<(N + 63) / 64, 256, 0, stream>>>(head, Wo, bo, N);
}

// Round 3
// 522.674 us; speedup vs baseline: 3.2611x; 1.3169x over previous
//
#include <hip/hip_runtime.h>
#include <math.h>

#define DD 128
typedef unsigned int u32;

__device__ __forceinline__ float4 f4zero() { return make_float4(0.f, 0.f, 0.f, 0.f); }
__device__ __forceinline__ void fma4(float4& a, float s, const float4& w) {
    a.x = fmaf(s, w.x, a.x);
    a.y = fmaf(s, w.y, a.y);
    a.z = fmaf(s, w.z, a.z);
    a.w = fmaf(s, w.w, a.w);
}
// round-to-nearest-even f32 -> bf16 (as low 16 bits of u32)
__device__ __forceinline__ u32 bf16rne(float f) {
    u32 u = __float_as_uint(f);
    u += 0x7FFFu + ((u >> 16) & 1u);
    return u >> 16;
}
__device__ __forceinline__ u32 pack2(float lo, float hi) {
    return bf16rne(lo) | (bf16rne(hi) << 16);
}
__device__ __forceinline__ float unlo(u32 u) { return __uint_as_float(u << 16); }
__device__ __forceinline__ float unhi(u32 u) { return __uint_as_float(u & 0xFFFF0000u); }

// ---------------------------------------------------------------------------
// Kernel 1: compose weights.
//   Wqp = Wq@We1, Wkp = Wk@We1, Wp2e = Wp2@We1, bKP = bp2@We1 + be1
// ---------------------------------------------------------------------------
__global__ __launch_bounds__(128) void compose_weights(
    const float* __restrict__ Wq, const float* __restrict__ Wk,
    const float* __restrict__ We1, const float* __restrict__ Wp2,
    const float* __restrict__ bp2, const float* __restrict__ be1,
    float* __restrict__ Wqp, float* __restrict__ Wkp,
    float* __restrict__ Wp2e, float* __restrict__ bKP) {
    int i = blockIdx.x;
    int j = threadIdx.x;
    float aq = 0.f, ak = 0.f;
    for (int k = 0; k < DD; ++k) {
        float w = We1[k * DD + j];
        aq = fmaf(Wq[i * DD + k], w, aq);
        ak = fmaf(Wk[i * DD + k], w, ak);
    }
    Wqp[i * DD + j] = aq;
    Wkp[i * DD + j] = ak;
    if (i < 3) {
        float a = 0.f;
        for (int k = 0; k < DD; ++k) a = fmaf(Wp2[i * DD + k], We1[k * DD + j], a);
        Wp2e[i * DD + j] = a;
    }
    if (i == 3) {
        float a = be1[j];
        for (int k = 0; k < DD; ++k) a = fmaf(bp2[k], We1[k * DD + j], a);
        bKP[j] = a;
    }
}

// ---------------------------------------------------------------------------
// Kernel 2: node projections. fp32 math; bf16-packed outputs.
//   QWb[n][j]  : u32 = (q_{2j} lo | q_{2j+1} hi)            [N][64]
//   SPb[n][j]  : u32 = (KPW_j lo | VP_j hi)                 [N][128]
// ---------------------------------------------------------------------------
__global__ __launch_bounds__(256) void node_proj(
    const float* __restrict__ h, const float* __restrict__ c,
    const float* __restrict__ Wqp, const float* __restrict__ Wkp,
    const float* __restrict__ Wv, const float* __restrict__ Wp1,
    const float* __restrict__ bp1, const float* __restrict__ Wp2,
    const float* __restrict__ bp2, const float* __restrict__ Wp2e,
    const float* __restrict__ bKP,
    u32* __restrict__ QWb, u32* __restrict__ SPb, int N) {
    __shared__ float h_lds[64 * DD];
    __shared__ float u_lds[64 * 4];

    const int row0 = blockIdx.x * 64;
    const int t = threadIdx.x;

#pragma unroll
    for (int i = 0; i < 8; ++i) {
        int f = t + i * 256;
        int row = f >> 5;
        int cq = f & 31;
        float4 v = f4zero();
        if (row0 + row < N) v = *(const float4*)&h[(size_t)(row0 + row) * DD + cq * 4];
        *(float4*)&h_lds[row * DD + cq * 4] = v;
    }
    if (t < 192) {
        int row = t / 3;
        int i = t - row * 3;
        float u = 0.f;
        if (row0 + row < N) {
            const float* cr = &c[(size_t)(row0 + row) * 3];
            u = bp1[i];
            u = fmaf(cr[0], Wp1[0 * 3 + i], u);
            u = fmaf(cr[1], Wp1[1 * 3 + i], u);
            u = fmaf(cr[2], Wp1[2 * 3 + i], u);
            u = fmaxf(u, 0.f);
        }
        u_lds[row * 4 + i] = u;
    }
    __syncthreads();

    const int cg = t & 31;
    const int rg = t >> 5;

    float4 aq[8], ak[8], av[8];
#pragma unroll
    for (int r = 0; r < 8; ++r) { aq[r] = f4zero(); ak[r] = f4zero(); av[r] = f4zero(); }

    for (int k = 0; k < DD; ++k) {
        float4 wq = *(const float4*)&Wqp[k * DD + cg * 4];
        float4 wk = *(const float4*)&Wkp[k * DD + cg * 4];
        float4 wv = *(const float4*)&Wv[k * DD + cg * 4];
#pragma unroll
        for (int r = 0; r < 8; ++r) {
            float hv = h_lds[(rg * 8 + r) * DD + k];
            fma4(aq[r], hv, wq);
            fma4(ak[r], hv, wk);
            fma4(av[r], hv, wv);
        }
    }

    float4 e0 = *(const float4*)&Wp2e[0 * DD + cg * 4];
    float4 e1 = *(const float4*)&Wp2e[1 * DD + cg * 4];
    float4 e2 = *(const float4*)&Wp2e[2 * DD + cg * 4];
    float4 p0 = *(const float4*)&Wp2[0 * DD + cg * 4];
    float4 p1 = *(const float4*)&Wp2[1 * DD + cg * 4];
    float4 p2 = *(const float4*)&Wp2[2 * DD + cg * 4];
    float4 bk = *(const float4*)&bKP[cg * 4];
    float4 bp = *(const float4*)&bp2[cg * 4];

#pragma unroll
    for (int r = 0; r < 8; ++r) {
        int row = rg * 8 + r;
        if (row0 + row >= N) continue;
        float u0 = u_lds[row * 4 + 0];
        float u1 = u_lds[row * 4 + 1];
        float u2 = u_lds[row * 4 + 2];

        float4 K = ak[r];
        fma4(K, u0, e0); fma4(K, u1, e1); fma4(K, u2, e2);
        K.x += bk.x; K.y += bk.y; K.z += bk.z; K.w += bk.w;

        float4 V = av[r];
        fma4(V, u0, p0); fma4(V, u1, p1); fma4(V, u2, p2);
        V.x += bp.x; V.y += bp.y; V.z += bp.z; V.w += bp.w;

        uint2 qv;
        qv.x = pack2(aq[r].x, aq[r].y);
        qv.y = pack2(aq[r].z, aq[r].w);
        *(uint2*)&QWb[(size_t)(row0 + row) * 64 + cg * 2] = qv;

        uint4 sv;
        sv.x = pack2(K.x, V.x);
        sv.y = pack2(K.y, V.y);
        sv.z = pack2(K.z, V.z);
        sv.w = pack2(K.w, V.w);
        *(uint4*)&SPb[(size_t)(row0 + row) * 128 + cg * 4] = sv;
    }
}

// ---------------------------------------------------------------------------
// Counting sort of edges by dst -> CSR.
// ---------------------------------------------------------------------------
__global__ __launch_bounds__(256) void k_hist(const int* __restrict__ dst,
                                              int* __restrict__ deg, int E) {
    int i = blockIdx.x * 256 + threadIdx.x;
    int stride = gridDim.x * 256;
    for (; i < E; i += stride) atomicAdd(&deg[dst[i]], 1);
}

__global__ __launch_bounds__(256) void k_scan1(const int* __restrict__ deg,
                                               int* __restrict__ offs,
                                               int* __restrict__ blockSums, int n) {
    __shared__ int ts[256];
    int b = blockIdx.x, t = threadIdx.x;
    int base = b * 2048 + t * 8;
    int v[8];
    int s = 0;
#pragma unroll
    for (int i = 0; i < 8; ++i) {
        int idx = base + i;
        v[i] = (idx < n) ? deg[idx] : 0;
        s += v[i];
    }
    ts[t] = s;
    __syncthreads();
    for (int off = 1; off < 256; off <<= 1) {
        int x = (t >= off) ? ts[t - off] : 0;
        __syncthreads();
        ts[t] += x;
        __syncthreads();
    }
    int run = ts[t] - s;
    if (t == 255) blockSums[b] = ts[255];
#pragma unroll
    for (int i = 0; i < 8; ++i) {
        int idx = base + i;
        if (idx < n) offs[idx] = run;
        run += v[i];
    }
}

__global__ __launch_bounds__(256) void k_scan2(int* __restrict__ bs, int nb) {
    __shared__ int s[256];
    int t = threadIdx.x;
    int orig = (t < nb) ? bs[t] : 0;
    s[t] = orig;
    __syncthreads();
    for (int off = 1; off < 256; off <<= 1) {
        int x = (t >= off) ? s[t - off] : 0;
        __syncthreads();
        s[t] += x;
        __syncthreads();
    }
    if (t < nb) bs[t] = s[t] - orig;
}

__global__ __launch_bounds__(256) void k_scan3(int* __restrict__ offs,
                                               int* __restrict__ cursor,
                                               const int* __restrict__ bs,
                                               int n, int E) {
    int b = blockIdx.x, t = threadIdx.x;
    int add = bs[b];
    int base = b * 2048 + t * 8;
#pragma unroll
    for (int i = 0; i < 8; ++i) {
        int idx = base + i;
        if (idx < n) {
            int o = offs[idx] + add;
            offs[idx] = o;
            cursor[idx] = o;
        }
    }
    if (b == gridDim.x - 1 && t == 255) offs[n] = E;
}

__global__ __launch_bounds__(256) void k_scatter(const int* __restrict__ src,
                                                 const int* __restrict__ dst,
                                                 int* __restrict__ cursor,
                                                 int* __restrict__ ssrc, int E) {
    int i = blockIdx.x * 256 + threadIdx.x;
    int stride = gridDim.x * 256;
    for (; i < E; i += stride) {
        int d = dst[i];
        int pos = atomicAdd(&cursor[d], 1);
        ssrc[pos] = src[i];
    }
}

// ---------------------------------------------------------------------------
// Kernel 3: CSR aggregate — one wave per dst node, bf16 gathers, fp32 math.
// ---------------------------------------------------------------------------
__global__ __launch_bounds__(256) void aggregate(
    const int* __restrict__ offs, const int* __restrict__ ssrc,
    const u32* __restrict__ SPb, const u32* __restrict__ QWb,
    const float* __restrict__ We2, const float* __restrict__ be2,
    u32* __restrict__ headb, int N) {
    const int node = (blockIdx.x * 256 + threadIdx.x) >> 6;
    const int lane = threadIdx.x & 63;
    if (node >= N) return;

    const float INVS = 0.08838834764831845f;  // 1/sqrt(128)
    u32 qu = QWb[(size_t)node * 64 + lane];
    float q0 = unlo(qu), q1 = unhi(qu);
    float2 w2 = *(const float2*)&We2[lane * 2];
    float b2 = be2[0];

    int beg = offs[node], end = offs[node + 1];
    float acc0 = 0.f, acc1 = 0.f, zacc = 0.f;

    int e = beg;
    for (; e + 3 < end; e += 4) {
        int s0 = ssrc[e], s1 = ssrc[e + 1], s2 = ssrc[e + 2], s3 = ssrc[e + 3];
        uint2 u0 = *(const uint2*)&SPb[(size_t)s0 * 128 + lane * 2];
        uint2 u1 = *(const uint2*)&SPb[(size_t)s1 * 128 + lane * 2];
        uint2 u2 = *(const uint2*)&SPb[(size_t)s2 * 128 + lane * 2];
        uint2 u3 = *(const uint2*)&SPb[(size_t)s3 * 128 + lane * 2];

        float p0 = fmaf(fmaxf(unlo(u0.x) - q0, 0.f), w2.x, fmaxf(unlo(u0.y) - q1, 0.f) * w2.y);
        float p1 = fmaf(fmaxf(unlo(u1.x) - q0, 0.f), w2.x, fmaxf(unlo(u1.y) - q1, 0.f) * w2.y);
        float p2 = fmaf(fmaxf(unlo(u2.x) - q0, 0.f), w2.x, fmaxf(unlo(u2.y) - q1, 0.f) * w2.y);
        float p3 = fmaf(fmaxf(unlo(u3.x) - q0, 0.f), w2.x, fmaxf(unlo(u3.y) - q1, 0.f) * w2.y);
#pragma unroll
        for (int off = 32; off; off >>= 1) {
            p0 += __shfl_xor(p0, off);
            p1 += __shfl_xor(p1, off);
            p2 += __shfl_xor(p2, off);
            p3 += __shfl_xor(p3, off);
        }
        float sc0 = __expf(fminf(fmaxf((p0 + b2) * INVS, -5.f), 5.f));
        float sc1 = __expf(fminf(fmaxf((p1 + b2) * INVS, -5.f), 5.f));
        float sc2 = __expf(fminf(fmaxf((p2 + b2) * INVS, -5.f), 5.f));
        float sc3 = __expf(fminf(fmaxf((p3 + b2) * INVS, -5.f), 5.f));

        acc0 = fmaf(unhi(u0.x), sc0, acc0); acc1 = fmaf(unhi(u0.y), sc0, acc1);
        acc0 = fmaf(unhi(u1.x), sc1, acc0); acc1 = fmaf(unhi(u1.y), sc1, acc1);
        acc0 = fmaf(unhi(u2.x), sc2, acc0); acc1 = fmaf(unhi(u2.y), sc2, acc1);
        acc0 = fmaf(unhi(u3.x), sc3, acc0); acc1 = fmaf(unhi(u3.y), sc3, acc1);
        zacc += (sc0 + sc1) + (sc2 + sc3);
    }
    for (; e < end; ++e) {
        int s0 = ssrc[e];
        uint2 u0 = *(const uint2*)&SPb[(size_t)s0 * 128 + lane * 2];
        float p0 = fmaf(fmaxf(unlo(u0.x) - q0, 0.f), w2.x, fmaxf(unlo(u0.y) - q1, 0.f) * w2.y);
#pragma unroll
        for (int off = 32; off; off >>= 1) p0 += __shfl_xor(p0, off);
        float sc0 = __expf(fminf(fmaxf((p0 + b2) * INVS, -5.f), 5.f));
        acc0 = fmaf(unhi(u0.x), sc0, acc0);
        acc1 = fmaf(unhi(u0.y), sc0, acc1);
        zacc += sc0;
    }

    float rz = 1.0f / zacc;
    headb[(size_t)node * 64 + lane] = pack2(acc0 * rz, acc1 * rz);
}

// ---------------------------------------------------------------------------
// Kernel 4: out = head @ Wo + bo (head bf16-packed, out fp32).
// ---------------------------------------------------------------------------
__global__ __launch_bounds__(256) void out_proj(
    const u32* __restrict__ headb, const float* __restrict__ Wo,
    const float* __restrict__ bo, float* __restrict__ out, int N) {
    __shared__ float a_lds[64 * DD];
    const int row0 = blockIdx.x * 64;
    const int t = threadIdx.x;

#pragma unroll
    for (int i = 0; i < 4; ++i) {
        int f = t + i * 256;     // 1024 uint4 slots (64 rows x 16)
        int row = f >> 4;
        int cq = f & 15;
        uint4 v = make_uint4(0, 0, 0, 0);
        if (row0 + row < N) v = *(const uint4*)&headb[(size_t)(row0 + row) * 64 + cq * 4];
        float* d = &a_lds[row * DD + cq * 8];
        d[0] = unlo(v.x); d[1] = unhi(v.x);
        d[2] = unlo(v.y); d[3] = unhi(v.y);
        d[4] = unlo(v.z); d[5] = unhi(v.z);
        d[6] = unlo(v.w); d[7] = unhi(v.w);
    }
    __syncthreads();

    const int cg = t & 31;
    const int rg = t >> 5;
    float4 acc[8];
#pragma unroll
    for (int r = 0; r < 8; ++r) acc[r] = f4zero();

    for (int k = 0; k < DD; ++k) {
        float4 wo = *(const float4*)&Wo[k * DD + cg * 4];
#pragma unroll
        for (int r = 0; r < 8; ++r) {
            float hv = a_lds[(rg * 8 + r) * DD + k];
            fma4(acc[r], hv, wo);
        }
    }

    float4 b = *(const float4*)&bo[cg * 4];
#pragma unroll
    for (int r = 0; r < 8; ++r) {
        int row = rg * 8 + r;
        if (row0 + row >= N) continue;
        float4 o = acc[r];
        o.x += b.x; o.y += b.y; o.z += b.z; o.w += b.w;
        *(float4*)&out[(size_t)(row0 + row) * DD + cg * 4] = o;
    }
}

// ---------------------------------------------------------------------------
extern "C" void kernel_launch(void* const* d_in, const int* in_sizes, int n_in,
                              void* d_out, int out_size, void* d_ws, size_t ws_size,
                              hipStream_t stream) {
    const float* h   = (const float*)d_in[0];
    const float* c   = (const float*)d_in[1];
    const int*   src = (const int*)d_in[2];
    const int*   dst = (const int*)d_in[3];
    const float* Wq  = (const float*)d_in[4];
    const float* Wk  = (const float*)d_in[5];
    const float* Wv  = (const float*)d_in[6];
    const float* Wp1 = (const float*)d_in[7];
    const float* bp1 = (const float*)d_in[8];
    const float* Wp2 = (const float*)d_in[9];
    const float* bp2 = (const float*)d_in[10];
    const float* We1 = (const float*)d_in[11];
    const float* be1 = (const float*)d_in[12];
    const float* We2 = (const float*)d_in[13];
    const float* be2 = (const float*)d_in[14];
    const float* Wo  = (const float*)d_in[15];
    const float* bo  = (const float*)d_in[16];

    const int N = in_sizes[0] / DD;
    const int E = in_sizes[2];

    float* ws   = (float*)d_ws;
    float* Wqp  = ws;                       // 128*128
    float* Wkp  = Wqp + DD * DD;            // 128*128
    float* Wp2e = Wkp + DD * DD;            // 3*128
    float* bKP  = Wp2e + 3 * DD;            // 128
    u32*   QWb  = (u32*)(bKP + DD);         // N*64
    u32*   SPb  = QWb + (size_t)N * 64;     // N*128
    u32*   headb = SPb + (size_t)N * 128;   // N*64
    int*   offs   = (int*)(headb + (size_t)N * 64);  // N+1
    int*   cursor = offs + (N + 1);                  // N+1 (also deg)
    int*   bsums  = cursor + (N + 1);                // 64
    int*   ssrc   = bsums + 64;                      // E

    const int NB = (N + 2047) / 2048;

    hipMemsetAsync(cursor, 0, (size_t)(N + 1) * sizeof(int), stream);

    compose_weights<<<DD, DD, 0, stream>>>(Wq, Wk, We1, Wp2, bp2, be1,
                                           Wqp, Wkp, Wp2e, bKP);

    node_proj<<<(N + 63) / 64, 256, 0, stream>>>(h, c, Wqp, Wkp, Wv, Wp1, bp1,
                                                 Wp2, bp2, Wp2e, bKP, QWb, SPb, N);

    k_hist<<<2048, 256, 0, stream>>>(dst, cursor, E);
    k_scan1<<<NB, 256, 0, stream>>>(cursor, offs, bsums, N);
    k_scan2<<<1, 256, 0, stream>>>(bsums, NB);
    k_scan3<<<NB, 256, 0, stream>>>(offs, cursor, bsums, N, E);
    k_scatter<<<2048, 256, 0, stream>>>(src, dst, cursor, ssrc, E);

    aggregate<<<(N * 64 + 255) / 256, 256, 0, stream>>>(offs, ssrc, SPb, QWb,
                                                        We2, be2, headb, N);

    out_proj<<<(N + 63) / 64, 256, 0, stream>>>(headb, Wo, bo, (float*)d_out, N);
}

// Round 4
// 419.107 us; speedup vs baseline: 4.0669x; 1.2471x over previous
//
#include <hip/hip_runtime.h>
#include <math.h>

#define DD 128
typedef unsigned int u32;
typedef __attribute__((ext_vector_type(8))) short bf16x8;
typedef __attribute__((ext_vector_type(4))) float f32x4;

__device__ __forceinline__ float4 f4zero() { return make_float4(0.f, 0.f, 0.f, 0.f); }
// round-to-nearest-even f32 -> bf16 (low 16 bits)
__device__ __forceinline__ u32 bf16rne(float f) {
    u32 u = __float_as_uint(f);
    u += 0x7FFFu + ((u >> 16) & 1u);
    return u >> 16;
}
__device__ __forceinline__ u32 pack2(float lo, float hi) {
    return bf16rne(lo) | (bf16rne(hi) << 16);
}
__device__ __forceinline__ float unlo(u32 u) { return __uint_as_float(u << 16); }
__device__ __forceinline__ float unhi(u32 u) { return __uint_as_float(u & 0xFFFF0000u); }

// ---------------------------------------------------------------------------
// Kernel 1: compose weights directly into MFMA B-fragment order (bf16).
// Node GEMM B' is [K=160][384]:
//   col tiles ct=0..23, ct = 6u + r (u=wave 0..3, r=0..5):
//     r 0,1 -> Q  cols n = 32u + 16r + c      (B rows: Wq@We1; rows>=128: 0)
//     r 2,3 -> K  cols n = 32u + 16(r&1) + c  (rows<128: Wk@We1; 128-130: Wp2@We1; 131: bp2@We1+be1)
//     r 4,5 -> V  cols n = 32u + 16(r&1) + c  (rows<128: Wv; 128-130: Wp2; 131: bp2)
// B-frag layout: lane l holds col n(ct, l&15), k = ks*32 + (l>>4)*8 + j (j=0..7).
// Blocks 0..119: node B' (ct*5+ks). Blocks 120..151: Wo fragments (ct*4+ks).
// ---------------------------------------------------------------------------
__global__ __launch_bounds__(64) void compose_frags(
    const float* __restrict__ Wq, const float* __restrict__ Wk,
    const float* __restrict__ Wv, const float* __restrict__ We1,
    const float* __restrict__ be1, const float* __restrict__ Wp2,
    const float* __restrict__ bp2, const float* __restrict__ Wo,
    u32* __restrict__ BF) {
    const int bid = blockIdx.x;
    const int l = threadIdx.x;
    const int c = l & 15;
    const int kg = l >> 4;
    float val[8];

    if (bid < 120) {
        const int ct = bid / 5, ks = bid - ct * 5;
        const int u = ct / 6, r = ct - u * 6;
        const int n = 32 * u + 16 * (r < 2 ? r : (r & 1)) + c;
#pragma unroll
        for (int j = 0; j < 8; ++j) {
            const int k = ks * 32 + kg * 8 + j;
            float v = 0.f;
            if (r < 2) {  // Q section
                if (k < 128) {
                    float a = 0.f;
                    for (int t = 0; t < 128; ++t)
                        a = fmaf(Wq[k * 128 + t], We1[t * 128 + n], a);
                    v = a;
                }
            } else if (r < 4) {  // K section
                if (k < 128) {
                    float a = 0.f;
                    for (int t = 0; t < 128; ++t)
                        a = fmaf(Wk[k * 128 + t], We1[t * 128 + n], a);
                    v = a;
                } else if (k < 131) {
                    float a = 0.f;
                    for (int t = 0; t < 128; ++t)
                        a = fmaf(Wp2[(k - 128) * 128 + t], We1[t * 128 + n], a);
                    v = a;
                } else if (k == 131) {
                    float a = be1[n];
                    for (int t = 0; t < 128; ++t)
                        a = fmaf(bp2[t], We1[t * 128 + n], a);
                    v = a;
                }
            } else {  // V section
                if (k < 128) v = Wv[k * 128 + n];
                else if (k < 131) v = Wp2[(k - 128) * 128 + n];
                else if (k == 131) v = bp2[n];
            }
            val[j] = v;
        }
    } else {  // Wo fragments
        const int b2 = bid - 120;
        const int ct = b2 >> 2, ks = b2 & 3;
        const int n = ct * 16 + c;
#pragma unroll
        for (int j = 0; j < 8; ++j) {
            const int k = ks * 32 + kg * 8 + j;
            val[j] = Wo[k * 128 + n];
        }
    }
    u32* dst = &BF[((size_t)bid * 64 + l) * 4];
    dst[0] = pack2(val[0], val[1]);
    dst[1] = pack2(val[2], val[3]);
    dst[2] = pack2(val[4], val[5]);
    dst[3] = pack2(val[6], val[7]);
}

// ---------------------------------------------------------------------------
// Kernel 2: node projections as one MFMA GEMM [N x 160] @ [160 x 384].
// A row: [h(128) | u0 u1 u2 1 | zeros(28)] in LDS bf16, XOR-swizzled.
// Wave w (of 4) computes all 64 rows x col tiles ct = 6w..6w+5.
// Outputs: QWb[n][m*16+c] = pack(Q[32m+c], Q[32m+16+c])
//          SPb[n][32m+2c+hi] = pack(K[32m+16hi+c], V[32m+16hi+c])
// ---------------------------------------------------------------------------
__global__ __launch_bounds__(256) void node_mfma(
    const float* __restrict__ h, const float* __restrict__ c,
    const float* __restrict__ Wp1, const float* __restrict__ bp1,
    const u32* __restrict__ BF,
    u32* __restrict__ QWb, u32* __restrict__ SPb, int N) {
    __shared__ u32 hs[64 * 96];  // 64 rows x 384 B (160 bf16 + pad), swizzled

    const int row0 = blockIdx.x * 64;
    const int t = threadIdx.x;

    // stage h (fp32 -> bf16), swizzled: dword = row*96 + (colD ^ ((row&7)<<2))
#pragma unroll
    for (int i = 0; i < 8; ++i) {
        int f = t + i * 256;
        int row = f >> 5;
        int cq = f & 31;
        float4 v = f4zero();
        if (row0 + row < N) v = *(const float4*)&h[(size_t)(row0 + row) * DD + cq * 4];
        int idx = row * 96 + ((cq * 2) ^ ((row & 7) << 2));
        uint2 p;
        p.x = pack2(v.x, v.y);
        p.y = pack2(v.z, v.w);
        *(uint2*)&hs[idx] = p;
    }
    // tail: cols 128..159 = [u0,u1,u2,1, zeros]; one thread per row
    if (t < 64) {
        int row = t;
        float u0 = 0.f, u1 = 0.f, u2 = 0.f;
        if (row0 + row < N) {
            const float* cr = &c[(size_t)(row0 + row) * 3];
            float c0 = cr[0], c1 = cr[1], c2 = cr[2];
            u0 = fmaxf(bp1[0] + c0 * Wp1[0] + c1 * Wp1[3] + c2 * Wp1[6], 0.f);
            u1 = fmaxf(bp1[1] + c0 * Wp1[1] + c1 * Wp1[4] + c2 * Wp1[7], 0.f);
            u2 = fmaxf(bp1[2] + c0 * Wp1[2] + c1 * Wp1[5] + c2 * Wp1[8], 0.f);
        }
        int swz = (row & 7) << 2;
        uint4 z0 = make_uint4(pack2(u0, u1), pack2(u2, 1.0f), 0u, 0u);
        uint4 zz = make_uint4(0u, 0u, 0u, 0u);
#pragma unroll
        for (int q = 0; q < 4; ++q) {
            int idx = row * 96 + 64 + ((q * 4) ^ swz);
            *(uint4*)&hs[idx] = (q == 0) ? z0 : zz;
        }
    }
    __syncthreads();

    const int w = t >> 6, l = t & 63;
    const int cc = l & 15, kg = l >> 4;

    f32x4 acc[4][6];
#pragma unroll
    for (int rt = 0; rt < 4; ++rt)
#pragma unroll
        for (int r = 0; r < 6; ++r) acc[rt][r] = (f32x4){0.f, 0.f, 0.f, 0.f};

#pragma unroll
    for (int ks = 0; ks < 5; ++ks) {
        bf16x8 a[4];
#pragma unroll
        for (int rt = 0; rt < 4; ++rt) {
            int row = rt * 16 + cc;
            int idx = row * 96 + ((ks * 16 + kg * 4) ^ ((row & 7) << 2));
            a[rt] = *(const bf16x8*)&hs[idx];
        }
#pragma unroll
        for (int r = 0; r < 6; ++r) {
            const bf16x8 b = *(const bf16x8*)&BF[(((size_t)(w * 6 + r) * 5 + ks) * 64 + l) * 4];
#pragma unroll
            for (int rt = 0; rt < 4; ++rt)
                acc[rt][r] = __builtin_amdgcn_mfma_f32_16x16x32_bf16(a[rt], b, acc[rt][r], 0, 0, 0);
        }
    }

    // epilogue: D row = rt*16 + kg*4 + j, col tile per r
#pragma unroll
    for (int rt = 0; rt < 4; ++rt) {
#pragma unroll
        for (int j = 0; j < 4; ++j) {
            int row = row0 + rt * 16 + kg * 4 + j;
            if (row >= N) continue;
            // Q pair m=w: cols (32w+cc, 32w+16+cc)
            QWb[(size_t)row * 64 + w * 16 + cc] = pack2(acc[rt][0][j], acc[rt][1][j]);
            uint2 kv;
            kv.x = pack2(acc[rt][2][j], acc[rt][4][j]);  // col 32w+cc   (K,V)
            kv.y = pack2(acc[rt][3][j], acc[rt][5][j]);  // col 32w+16+cc
            *(uint2*)&SPb[(size_t)row * 128 + w * 32 + cc * 2] = kv;
        }
    }
}

// ---------------------------------------------------------------------------
// Counting sort of edges by dst -> CSR.
// ---------------------------------------------------------------------------
__global__ __launch_bounds__(256) void k_hist(const int* __restrict__ dst,
                                              int* __restrict__ deg, int E) {
    int i = blockIdx.x * 256 + threadIdx.x;
    int stride = gridDim.x * 256;
    for (; i < E; i += stride) atomicAdd(&deg[dst[i]], 1);
}

__global__ __launch_bounds__(256) void k_scan1(const int* __restrict__ deg,
                                               int* __restrict__ offs,
                                               int* __restrict__ blockSums, int n) {
    __shared__ int ts[256];
    int b = blockIdx.x, t = threadIdx.x;
    int base = b * 2048 + t * 8;
    int v[8];
    int s = 0;
#pragma unroll
    for (int i = 0; i < 8; ++i) {
        int idx = base + i;
        v[i] = (idx < n) ? deg[idx] : 0;
        s += v[i];
    }
    ts[t] = s;
    __syncthreads();
    for (int off = 1; off < 256; off <<= 1) {
        int x = (t >= off) ? ts[t - off] : 0;
        __syncthreads();
        ts[t] += x;
        __syncthreads();
    }
    int run = ts[t] - s;
    if (t == 255) blockSums[b] = ts[255];
#pragma unroll
    for (int i = 0; i < 8; ++i) {
        int idx = base + i;
        if (idx < n) offs[idx] = run;
        run += v[i];
    }
}

__global__ __launch_bounds__(256) void k_scan2(int* __restrict__ bs, int nb) {
    __shared__ int s[256];
    int t = threadIdx.x;
    int orig = (t < nb) ? bs[t] : 0;
    s[t] = orig;
    __syncthreads();
    for (int off = 1; off < 256; off <<= 1) {
        int x = (t >= off) ? s[t - off] : 0;
        __syncthreads();
        s[t] += x;
        __syncthreads();
    }
    if (t < nb) bs[t] = s[t] - orig;
}

__global__ __launch_bounds__(256) void k_scan3(int* __restrict__ offs,
                                               int* __restrict__ cursor,
                                               const int* __restrict__ bs,
                                               int n, int E) {
    int b = blockIdx.x, t = threadIdx.x;
    int add = bs[b];
    int base = b * 2048 + t * 8;
#pragma unroll
    for (int i = 0; i < 8; ++i) {
        int idx = base + i;
        if (idx < n) {
            int o = offs[idx] + add;
            offs[idx] = o;
            cursor[idx] = o;
        }
    }
    if (b == gridDim.x - 1 && t == 255) offs[n] = E;
}

__global__ __launch_bounds__(256) void k_scatter(const int* __restrict__ src,
                                                 const int* __restrict__ dst,
                                                 int* __restrict__ cursor,
                                                 int* __restrict__ ssrc, int E) {
    int i = blockIdx.x * 256 + threadIdx.x;
    int stride = gridDim.x * 256;
    for (; i < E; i += stride) {
        int d = dst[i];
        int pos = atomicAdd(&cursor[d], 1);
        ssrc[pos] = src[i];
    }
}

// ---------------------------------------------------------------------------
// Kernel 3: CSR aggregate — one wave per dst node, bf16 gathers, fp32 math.
// Lane L handles cols (32m+c, 32m+16+c), m = L>>4, c = L&15 (matches SPb/QWb).
// ---------------------------------------------------------------------------
__global__ __launch_bounds__(256) void aggregate(
    const int* __restrict__ offs, const int* __restrict__ ssrc,
    const u32* __restrict__ SPb, const u32* __restrict__ QWb,
    const float* __restrict__ We2, const float* __restrict__ be2,
    u32* __restrict__ headb, int N) {
    const int node = (blockIdx.x * 256 + threadIdx.x) >> 6;
    const int lane = threadIdx.x & 63;
    if (node >= N) return;

    const float INVS = 0.08838834764831845f;  // 1/sqrt(128)
    const int m = lane >> 4, cI = lane & 15;
    u32 qu = QWb[(size_t)node * 64 + lane];
    float q0 = unlo(qu), q1 = unhi(qu);
    float w2x = We2[32 * m + cI];
    float w2y = We2[32 * m + cI + 16];
    float b2 = be2[0];

    int beg = offs[node], end = offs[node + 1];
    float acc0 = 0.f, acc1 = 0.f, zacc = 0.f;

    int e = beg;
    for (; e + 3 < end; e += 4) {
        int s0 = ssrc[e], s1 = ssrc[e + 1], s2 = ssrc[e + 2], s3 = ssrc[e + 3];
        uint2 u0 = *(const uint2*)&SPb[(size_t)s0 * 128 + lane * 2];
        uint2 u1 = *(const uint2*)&SPb[(size_t)s1 * 128 + lane * 2];
        uint2 u2 = *(const uint2*)&SPb[(size_t)s2 * 128 + lane * 2];
        uint2 u3 = *(const uint2*)&SPb[(size_t)s3 * 128 + lane * 2];

        float p0 = fmaf(fmaxf(unlo(u0.x) - q0, 0.f), w2x, fmaxf(unlo(u0.y) - q1, 0.f) * w2y);
        float p1 = fmaf(fmaxf(unlo(u1.x) - q0, 0.f), w2x, fmaxf(unlo(u1.y) - q1, 0.f) * w2y);
        float p2 = fmaf(fmaxf(unlo(u2.x) - q0, 0.f), w2x, fmaxf(unlo(u2.y) - q1, 0.f) * w2y);
        float p3 = fmaf(fmaxf(unlo(u3.x) - q0, 0.f), w2x, fmaxf(unlo(u3.y) - q1, 0.f) * w2y);
#pragma unroll
        for (int off = 32; off; off >>= 1) {
            p0 += __shfl_xor(p0, off);
            p1 += __shfl_xor(p1, off);
            p2 += __shfl_xor(p2, off);
            p3 += __shfl_xor(p3, off);
        }
        float sc0 = __expf(fminf(fmaxf((p0 + b2) * INVS, -5.f), 5.f));
        float sc1 = __expf(fminf(fmaxf((p1 + b2) * INVS, -5.f), 5.f));
        float sc2 = __expf(fminf(fmaxf((p2 + b2) * INVS, -5.f), 5.f));
        float sc3 = __expf(fminf(fmaxf((p3 + b2) * INVS, -5.f), 5.f));

        acc0 = fmaf(unhi(u0.x), sc0, acc0); acc1 = fmaf(unhi(u0.y), sc0, acc1);
        acc0 = fmaf(unhi(u1.x), sc1, acc0); acc1 = fmaf(unhi(u1.y), sc1, acc1);
        acc0 = fmaf(unhi(u2.x), sc2, acc0); acc1 = fmaf(unhi(u2.y), sc2, acc1);
        acc0 = fmaf(unhi(u3.x), sc3, acc0); acc1 = fmaf(unhi(u3.y), sc3, acc1);
        zacc += (sc0 + sc1) + (sc2 + sc3);
    }
    for (; e < end; ++e) {
        int s0 = ssrc[e];
        uint2 u0 = *(const uint2*)&SPb[(size_t)s0 * 128 + lane * 2];
        float p0 = fmaf(fmaxf(unlo(u0.x) - q0, 0.f), w2x, fmaxf(unlo(u0.y) - q1, 0.f) * w2y);
#pragma unroll
        for (int off = 32; off; off >>= 1) p0 += __shfl_xor(p0, off);
        float sc0 = __expf(fminf(fmaxf((p0 + b2) * INVS, -5.f), 5.f));
        acc0 = fmaf(unhi(u0.x), sc0, acc0);
        acc1 = fmaf(unhi(u0.y), sc0, acc1);
        zacc += sc0;
    }

    float rz = 1.0f / zacc;
    headb[(size_t)node * 64 + lane] = pack2(acc0 * rz, acc1 * rz);
}

// ---------------------------------------------------------------------------
// Kernel 4: out = head @ Wo + bo via MFMA. head slot L ↔ cols (32m+c, +16).
// Wave w owns col tiles {2w, 2w+1}.
// ---------------------------------------------------------------------------
__global__ __launch_bounds__(256) void out_mfma(
    const u32* __restrict__ headb, const u32* __restrict__ WoF,
    const float* __restrict__ bo, float* __restrict__ out, int N) {
    __shared__ u32 hs[64 * 64];  // 64 rows x 128 bf16, swizzled

    const int row0 = blockIdx.x * 64;
    const int t = threadIdx.x;

#pragma unroll
    for (int i = 0; i < 4; ++i) {
        int f = t + i * 256;  // 1024 uint4 slots
        int row = f >> 4;
        int cq = f & 15;
        uint4 v = make_uint4(0u, 0u, 0u, 0u);
        if (row0 + row < N) v = *(const uint4*)&headb[(size_t)(row0 + row) * 64 + cq * 4];
        int m = cq >> 2;
        int cb = (cq & 3) * 4;          // base col within 16-group
        int swz = (row & 7) << 2;
        // lo halves -> cols 32m+cb..+3 ; hi halves -> cols 32m+16+cb..+3
        uint2 A, B;
        A.x = (v.x & 0xFFFFu) | (v.y << 16);
        A.y = (v.z & 0xFFFFu) | (v.w << 16);
        B.x = (v.x >> 16) | (v.y & 0xFFFF0000u);
        B.y = (v.z >> 16) | (v.w & 0xFFFF0000u);
        int dA = 16 * m + (cb >> 1);
        *(uint2*)&hs[row * 64 + (dA ^ swz)] = A;
        *(uint2*)&hs[row * 64 + ((dA + 8) ^ swz)] = B;
    }
    __syncthreads();

    const int w = t >> 6, l = t & 63;
    const int cc = l & 15, kg = l >> 4;

    f32x4 acc[4][2];
#pragma unroll
    for (int rt = 0; rt < 4; ++rt) {
        acc[rt][0] = (f32x4){0.f, 0.f, 0.f, 0.f};
        acc[rt][1] = (f32x4){0.f, 0.f, 0.f, 0.f};
    }

#pragma unroll
    for (int ks = 0; ks < 4; ++ks) {
        bf16x8 a[4];
#pragma unroll
        for (int rt = 0; rt < 4; ++rt) {
            int row = rt * 16 + cc;
            int idx = row * 64 + ((ks * 16 + kg * 4) ^ ((row & 7) << 2));
            a[rt] = *(const bf16x8*)&hs[idx];
        }
#pragma unroll
        for (int ctl = 0; ctl < 2; ++ctl) {
            const bf16x8 b = *(const bf16x8*)&WoF[(((size_t)(2 * w + ctl) * 4 + ks) * 64 + l) * 4];
#pragma unroll
            for (int rt = 0; rt < 4; ++rt)
                acc[rt][ctl] = __builtin_amdgcn_mfma_f32_16x16x32_bf16(a[rt], b, acc[rt][ctl], 0, 0, 0);
        }
    }

#pragma unroll
    for (int ctl = 0; ctl < 2; ++ctl) {
        int col = (2 * w + ctl) * 16 + cc;
        float bias = bo[col];
#pragma unroll
        for (int rt = 0; rt < 4; ++rt) {
#pragma unroll
            for (int j = 0; j < 4; ++j) {
                int row = row0 + rt * 16 + kg * 4 + j;
                if (row >= N) continue;
                out[(size_t)row * DD + col] = acc[rt][ctl][j] + bias;
            }
        }
    }
}

// ---------------------------------------------------------------------------
extern "C" void kernel_launch(void* const* d_in, const int* in_sizes, int n_in,
                              void* d_out, int out_size, void* d_ws, size_t ws_size,
                              hipStream_t stream) {
    const float* h   = (const float*)d_in[0];
    const float* c   = (const float*)d_in[1];
    const int*   src = (const int*)d_in[2];
    const int*   dst = (const int*)d_in[3];
    const float* Wq  = (const float*)d_in[4];
    const float* Wk  = (const float*)d_in[5];
    const float* Wv  = (const float*)d_in[6];
    const float* Wp1 = (const float*)d_in[7];
    const float* bp1 = (const float*)d_in[8];
    const float* Wp2 = (const float*)d_in[9];
    const float* bp2 = (const float*)d_in[10];
    const float* We1 = (const float*)d_in[11];
    const float* be1 = (const float*)d_in[12];
    const float* We2 = (const float*)d_in[13];
    const float* be2 = (const float*)d_in[14];
    const float* Wo  = (const float*)d_in[15];
    const float* bo  = (const float*)d_in[16];

    const int N = in_sizes[0] / DD;
    const int E = in_sizes[2];

    u32* BF    = (u32*)d_ws;                 // 152*256 = 38912
    u32* WoF   = BF + 120 * 256;             // Wo fragment section
    u32* QWb   = BF + 152 * 256;             // N*64
    u32* SPb   = QWb + (size_t)N * 64;       // N*128
    u32* headb = SPb + (size_t)N * 128;      // N*64
    int* offs   = (int*)(headb + (size_t)N * 64);  // N+1
    int* cursor = offs + (N + 1);                  // N+1 (also deg)
    int* bsums  = cursor + (N + 1);                // 64
    int* ssrc   = bsums + 64;                      // E

    const int NB = (N + 2047) / 2048;

    hipMemsetAsync(cursor, 0, (size_t)(N + 1) * sizeof(int), stream);

    compose_frags<<<152, 64, 0, stream>>>(Wq, Wk, Wv, We1, be1, Wp2, bp2, Wo, BF);

    node_mfma<<<(N + 63) / 64, 256, 0, stream>>>(h, c, Wp1, bp1, BF, QWb, SPb, N);

    k_hist<<<2048, 256, 0, stream>>>(dst, cursor, E);
    k_scan1<<<NB, 256, 0, stream>>>(cursor, offs, bsums, N);
    k_scan2<<<1, 256, 0, stream>>>(bsums, NB);
    k_scan3<<<NB, 256, 0, stream>>>(offs, cursor, bsums, N, E);
    k_scatter<<<2048, 256, 0, stream>>>(src, dst, cursor, ssrc, E);

    aggregate<<<(N * 64 + 255) / 256, 256, 0, stream>>>(offs, ssrc, SPb, QWb,
                                                        We2, be2, headb, N);

    out_mfma<<<(N + 63) / 64, 256, 0, stream>>>(headb, WoF, bo, (float*)d_out, N);
}

// Round 5
// 266.231 us; speedup vs baseline: 6.4023x; 1.5742x over previous
//
#include <hip/hip_runtime.h>
#include <math.h>

#define DD 128
#define CAP 10240
typedef unsigned int u32;
typedef __attribute__((ext_vector_type(8))) short bf16x8;
typedef __attribute__((ext_vector_type(4))) float f32x4;

__device__ __forceinline__ float4 f4zero() { return make_float4(0.f, 0.f, 0.f, 0.f); }
// round-to-nearest-even f32 -> bf16 (low 16 bits)
__device__ __forceinline__ u32 bf16rne(float f) {
    u32 u = __float_as_uint(f);
    u += 0x7FFFu + ((u >> 16) & 1u);
    return u >> 16;
}
__device__ __forceinline__ u32 pack2(float lo, float hi) {
    return bf16rne(lo) | (bf16rne(hi) << 16);
}
__device__ __forceinline__ float unlo(u32 u) { return __uint_as_float(u << 16); }
__device__ __forceinline__ float unhi(u32 u) { return __uint_as_float(u & 0xFFFF0000u); }

// ---------------------------------------------------------------------------
// Kernel 1: compose weights directly into MFMA B-fragment order (bf16).
// (unchanged from R4 — verified)
// ---------------------------------------------------------------------------
__global__ __launch_bounds__(64) void compose_frags(
    const float* __restrict__ Wq, const float* __restrict__ Wk,
    const float* __restrict__ Wv, const float* __restrict__ We1,
    const float* __restrict__ be1, const float* __restrict__ Wp2,
    const float* __restrict__ bp2, const float* __restrict__ Wo,
    u32* __restrict__ BF) {
    const int bid = blockIdx.x;
    const int l = threadIdx.x;
    const int c = l & 15;
    const int kg = l >> 4;
    float val[8];

    if (bid < 120) {
        const int ct = bid / 5, ks = bid - ct * 5;
        const int u = ct / 6, r = ct - u * 6;
        const int n = 32 * u + 16 * (r < 2 ? r : (r & 1)) + c;
#pragma unroll
        for (int j = 0; j < 8; ++j) {
            const int k = ks * 32 + kg * 8 + j;
            float v = 0.f;
            if (r < 2) {  // Q section
                if (k < 128) {
                    float a = 0.f;
                    for (int t = 0; t < 128; ++t)
                        a = fmaf(Wq[k * 128 + t], We1[t * 128 + n], a);
                    v = a;
                }
            } else if (r < 4) {  // K section
                if (k < 128) {
                    float a = 0.f;
                    for (int t = 0; t < 128; ++t)
                        a = fmaf(Wk[k * 128 + t], We1[t * 128 + n], a);
                    v = a;
                } else if (k < 131) {
                    float a = 0.f;
                    for (int t = 0; t < 128; ++t)
                        a = fmaf(Wp2[(k - 128) * 128 + t], We1[t * 128 + n], a);
                    v = a;
                } else if (k == 131) {
                    float a = be1[n];
                    for (int t = 0; t < 128; ++t)
                        a = fmaf(bp2[t], We1[t * 128 + n], a);
                    v = a;
                }
            } else {  // V section
                if (k < 128) v = Wv[k * 128 + n];
                else if (k < 131) v = Wp2[(k - 128) * 128 + n];
                else if (k == 131) v = bp2[n];
            }
            val[j] = v;
        }
    } else {  // Wo fragments
        const int b2 = bid - 120;
        const int ct = b2 >> 2, ks = b2 & 3;
        const int n = ct * 16 + c;
#pragma unroll
        for (int j = 0; j < 8; ++j) {
            const int k = ks * 32 + kg * 8 + j;
            val[j] = Wo[k * 128 + n];
        }
    }
    u32* dst = &BF[((size_t)bid * 64 + l) * 4];
    dst[0] = pack2(val[0], val[1]);
    dst[1] = pack2(val[2], val[3]);
    dst[2] = pack2(val[4], val[5]);
    dst[3] = pack2(val[6], val[7]);
}

// ---------------------------------------------------------------------------
// Kernel 2: node projections as one MFMA GEMM [N x 160] @ [160 x 384].
// (unchanged from R4 — verified)
// ---------------------------------------------------------------------------
__global__ __launch_bounds__(256) void node_mfma(
    const float* __restrict__ h, const float* __restrict__ c,
    const float* __restrict__ Wp1, const float* __restrict__ bp1,
    const u32* __restrict__ BF,
    u32* __restrict__ QWb, u32* __restrict__ SPb, int N) {
    __shared__ u32 hs[64 * 96];  // 64 rows x 384 B (160 bf16 + pad), swizzled

    const int row0 = blockIdx.x * 64;
    const int t = threadIdx.x;

#pragma unroll
    for (int i = 0; i < 8; ++i) {
        int f = t + i * 256;
        int row = f >> 5;
        int cq = f & 31;
        float4 v = f4zero();
        if (row0 + row < N) v = *(const float4*)&h[(size_t)(row0 + row) * DD + cq * 4];
        int idx = row * 96 + ((cq * 2) ^ ((row & 7) << 2));
        uint2 p;
        p.x = pack2(v.x, v.y);
        p.y = pack2(v.z, v.w);
        *(uint2*)&hs[idx] = p;
    }
    if (t < 64) {
        int row = t;
        float u0 = 0.f, u1 = 0.f, u2 = 0.f;
        if (row0 + row < N) {
            const float* cr = &c[(size_t)(row0 + row) * 3];
            float c0 = cr[0], c1 = cr[1], c2 = cr[2];
            u0 = fmaxf(bp1[0] + c0 * Wp1[0] + c1 * Wp1[3] + c2 * Wp1[6], 0.f);
            u1 = fmaxf(bp1[1] + c0 * Wp1[1] + c1 * Wp1[4] + c2 * Wp1[7], 0.f);
            u2 = fmaxf(bp1[2] + c0 * Wp1[2] + c1 * Wp1[5] + c2 * Wp1[8], 0.f);
        }
        int swz = (row & 7) << 2;
        uint4 z0 = make_uint4(pack2(u0, u1), pack2(u2, 1.0f), 0u, 0u);
        uint4 zz = make_uint4(0u, 0u, 0u, 0u);
#pragma unroll
        for (int q = 0; q < 4; ++q) {
            int idx = row * 96 + 64 + ((q * 4) ^ swz);
            *(uint4*)&hs[idx] = (q == 0) ? z0 : zz;
        }
    }
    __syncthreads();

    const int w = t >> 6, l = t & 63;
    const int cc = l & 15, kg = l >> 4;

    f32x4 acc[4][6];
#pragma unroll
    for (int rt = 0; rt < 4; ++rt)
#pragma unroll
        for (int r = 0; r < 6; ++r) acc[rt][r] = (f32x4){0.f, 0.f, 0.f, 0.f};

#pragma unroll
    for (int ks = 0; ks < 5; ++ks) {
        bf16x8 a[4];
#pragma unroll
        for (int rt = 0; rt < 4; ++rt) {
            int row = rt * 16 + cc;
            int idx = row * 96 + ((ks * 16 + kg * 4) ^ ((row & 7) << 2));
            a[rt] = *(const bf16x8*)&hs[idx];
        }
#pragma unroll
        for (int r = 0; r < 6; ++r) {
            const bf16x8 b = *(const bf16x8*)&BF[(((size_t)(w * 6 + r) * 5 + ks) * 64 + l) * 4];
#pragma unroll
            for (int rt = 0; rt < 4; ++rt)
                acc[rt][r] = __builtin_amdgcn_mfma_f32_16x16x32_bf16(a[rt], b, acc[rt][r], 0, 0, 0);
        }
    }

#pragma unroll
    for (int rt = 0; rt < 4; ++rt) {
#pragma unroll
        for (int j = 0; j < 4; ++j) {
            int row = row0 + rt * 16 + kg * 4 + j;
            if (row >= N) continue;
            QWb[(size_t)row * 64 + w * 16 + cc] = pack2(acc[rt][0][j], acc[rt][1][j]);
            uint2 kv;
            kv.x = pack2(acc[rt][2][j], acc[rt][4][j]);
            kv.y = pack2(acc[rt][3][j], acc[rt][5][j]);
            *(uint2*)&SPb[(size_t)row * 128 + w * 32 + cc * 2] = kv;
        }
    }
}

// ---------------------------------------------------------------------------
// CSR build via two-pass LDS-ranked bucket sort (bucket = dst>>9, 512 nodes).
// ---------------------------------------------------------------------------
__global__ __launch_bounds__(256) void k_init(int* __restrict__ grange) {
    grange[threadIdx.x] = threadIdx.x * CAP;
}

// Pass 1: 4096 edges/block; LDS histogram + LDS returning-atomic rank;
// one global atomicAdd per (block, nonempty bucket); packed (src<<9|d&511).
__global__ __launch_bounds__(256) void p1_bucket(
    const int* __restrict__ src, const int* __restrict__ dst,
    int* __restrict__ grange, u32* __restrict__ ebuf, int E) {
    __shared__ int hist[256];
    __shared__ int base[256];
    const int t = threadIdx.x;
    hist[t] = 0;
    __syncthreads();
    const int chunk = blockIdx.x * 4096;
    int bk[16], rk[16];
    u32 pv[16];
#pragma unroll
    for (int i = 0; i < 16; ++i) {
        int idx = chunk + i * 256 + t;
        bk[i] = -1;
        if (idx < E) {
            int dd = dst[idx];
            int ss = src[idx];
            bk[i] = dd >> 9;
            pv[i] = ((u32)ss << 9) | (u32)(dd & 511);
            rk[i] = atomicAdd(&hist[bk[i]], 1);
        }
    }
    __syncthreads();
    if (hist[t]) base[t] = atomicAdd(&grange[t], hist[t]);
    __syncthreads();
#pragma unroll
    for (int i = 0; i < 16; ++i) {
        if (bk[i] >= 0) ebuf[base[bk[i]] + rk[i]] = pv[i];
    }
}

// Exclusive scan of the 256 bucket counts -> bucket_base.
__global__ __launch_bounds__(256) void k_scanB(const int* __restrict__ grange,
                                               int* __restrict__ bucket_base) {
    __shared__ int s[256];
    int t = threadIdx.x;
    int cnt = grange[t] - t * CAP;
    int orig = cnt;
    s[t] = cnt;
    __syncthreads();
    for (int off = 1; off < 256; off <<= 1) {
        int x = (t >= off) ? s[t - off] : 0;
        __syncthreads();
        s[t] += x;
        __syncthreads();
    }
    bucket_base[t] = s[t] - orig;
}

// Pass 2: one block per bucket. LDS count[512] -> LDS scan -> offs for the
// bucket's 512 nodes; LDS-cursor-ranked scatter of src ids into final CSR.
__global__ __launch_bounds__(256) void p2_local(
    const int* __restrict__ grange, const int* __restrict__ bucket_base,
    const u32* __restrict__ ebuf, int* __restrict__ ssrc,
    int* __restrict__ offs, int E) {
    __shared__ int cnt[512];
    __shared__ int cur[512];
    __shared__ int ts[256];
    const int r = blockIdx.x;
    const int t = threadIdx.x;
    const int cnt_r = grange[r] - r * CAP;
    const int base_r = bucket_base[r];
    cnt[t] = 0;
    cnt[t + 256] = 0;
    __syncthreads();
    const u32* eb = &ebuf[(size_t)r * CAP];
    for (int i = t; i < cnt_r; i += 256) atomicAdd(&cnt[eb[i] & 511], 1);
    __syncthreads();
    int v0 = cnt[2 * t], v1 = cnt[2 * t + 1];
    int pair = v0 + v1;
    ts[t] = pair;
    __syncthreads();
    for (int off = 1; off < 256; off <<= 1) {
        int x = (t >= off) ? ts[t - off] : 0;
        __syncthreads();
        ts[t] += x;
        __syncthreads();
    }
    int ex = ts[t] - pair;
    cur[2 * t] = ex;
    cur[2 * t + 1] = ex + v0;
    offs[r * 512 + 2 * t] = base_r + ex;
    offs[r * 512 + 2 * t + 1] = base_r + ex + v0;
    if (r == gridDim.x - 1 && t == 255) offs[gridDim.x * 512] = E;
    __syncthreads();
    for (int i = t; i < cnt_r; i += 256) {
        u32 e = eb[i];
        int p = atomicAdd(&cur[e & 511], 1);
        ssrc[base_r + p] = (int)(e >> 9);
    }
}

// ---------------------------------------------------------------------------
// Kernel 3: CSR aggregate (unchanged from R4 — verified).
// ---------------------------------------------------------------------------
__global__ __launch_bounds__(256) void aggregate(
    const int* __restrict__ offs, const int* __restrict__ ssrc,
    const u32* __restrict__ SPb, const u32* __restrict__ QWb,
    const float* __restrict__ We2, const float* __restrict__ be2,
    u32* __restrict__ headb, int N) {
    const int node = (blockIdx.x * 256 + threadIdx.x) >> 6;
    const int lane = threadIdx.x & 63;
    if (node >= N) return;

    const float INVS = 0.08838834764831845f;  // 1/sqrt(128)
    const int m = lane >> 4, cI = lane & 15;
    u32 qu = QWb[(size_t)node * 64 + lane];
    float q0 = unlo(qu), q1 = unhi(qu);
    float w2x = We2[32 * m + cI];
    float w2y = We2[32 * m + cI + 16];
    float b2 = be2[0];

    int beg = offs[node], end = offs[node + 1];
    float acc0 = 0.f, acc1 = 0.f, zacc = 0.f;

    int e = beg;
    for (; e + 3 < end; e += 4) {
        int s0 = ssrc[e], s1 = ssrc[e + 1], s2 = ssrc[e + 2], s3 = ssrc[e + 3];
        uint2 u0 = *(const uint2*)&SPb[(size_t)s0 * 128 + lane * 2];
        uint2 u1 = *(const uint2*)&SPb[(size_t)s1 * 128 + lane * 2];
        uint2 u2 = *(const uint2*)&SPb[(size_t)s2 * 128 + lane * 2];
        uint2 u3 = *(const uint2*)&SPb[(size_t)s3 * 128 + lane * 2];

        float p0 = fmaf(fmaxf(unlo(u0.x) - q0, 0.f), w2x, fmaxf(unlo(u0.y) - q1, 0.f) * w2y);
        float p1 = fmaf(fmaxf(unlo(u1.x) - q0, 0.f), w2x, fmaxf(unlo(u1.y) - q1, 0.f) * w2y);
        float p2 = fmaf(fmaxf(unlo(u2.x) - q0, 0.f), w2x, fmaxf(unlo(u2.y) - q1, 0.f) * w2y);
        float p3 = fmaf(fmaxf(unlo(u3.x) - q0, 0.f), w2x, fmaxf(unlo(u3.y) - q1, 0.f) * w2y);
#pragma unroll
        for (int off = 32; off; off >>= 1) {
            p0 += __shfl_xor(p0, off);
            p1 += __shfl_xor(p1, off);
            p2 += __shfl_xor(p2, off);
            p3 += __shfl_xor(p3, off);
        }
        float sc0 = __expf(fminf(fmaxf((p0 + b2) * INVS, -5.f), 5.f));
        float sc1 = __expf(fminf(fmaxf((p1 + b2) * INVS, -5.f), 5.f));
        float sc2 = __expf(fminf(fmaxf((p2 + b2) * INVS, -5.f), 5.f));
        float sc3 = __expf(fminf(fmaxf((p3 + b2) * INVS, -5.f), 5.f));

        acc0 = fmaf(unhi(u0.x), sc0, acc0); acc1 = fmaf(unhi(u0.y), sc0, acc1);
        acc0 = fmaf(unhi(u1.x), sc1, acc0); acc1 = fmaf(unhi(u1.y), sc1, acc1);
        acc0 = fmaf(unhi(u2.x), sc2, acc0); acc1 = fmaf(unhi(u2.y), sc2, acc1);
        acc0 = fmaf(unhi(u3.x), sc3, acc0); acc1 = fmaf(unhi(u3.y), sc3, acc1);
        zacc += (sc0 + sc1) + (sc2 + sc3);
    }
    for (; e < end; ++e) {
        int s0 = ssrc[e];
        uint2 u0 = *(const uint2*)&SPb[(size_t)s0 * 128 + lane * 2];
        float p0 = fmaf(fmaxf(unlo(u0.x) - q0, 0.f), w2x, fmaxf(unlo(u0.y) - q1, 0.f) * w2y);
#pragma unroll
        for (int off = 32; off; off >>= 1) p0 += __shfl_xor(p0, off);
        float sc0 = __expf(fminf(fmaxf((p0 + b2) * INVS, -5.f), 5.f));
        acc0 = fmaf(unhi(u0.x), sc0, acc0);
        acc1 = fmaf(unhi(u0.y), sc0, acc1);
        zacc += sc0;
    }

    float rz = 1.0f / zacc;
    headb[(size_t)node * 64 + lane] = pack2(acc0 * rz, acc1 * rz);
}

// ---------------------------------------------------------------------------
// Kernel 4: out = head @ Wo + bo via MFMA (unchanged from R4 — verified).
// ---------------------------------------------------------------------------
__global__ __launch_bounds__(256) void out_mfma(
    const u32* __restrict__ headb, const u32* __restrict__ WoF,
    const float* __restrict__ bo, float* __restrict__ out, int N) {
    __shared__ u32 hs[64 * 64];

    const int row0 = blockIdx.x * 64;
    const int t = threadIdx.x;

#pragma unroll
    for (int i = 0; i < 4; ++i) {
        int f = t + i * 256;
        int row = f >> 4;
        int cq = f & 15;
        uint4 v = make_uint4(0u, 0u, 0u, 0u);
        if (row0 + row < N) v = *(const uint4*)&headb[(size_t)(row0 + row) * 64 + cq * 4];
        int m = cq >> 2;
        int cb = (cq & 3) * 4;
        int swz = (row & 7) << 2;
        uint2 A, B;
        A.x = (v.x & 0xFFFFu) | (v.y << 16);
        A.y = (v.z & 0xFFFFu) | (v.w << 16);
        B.x = (v.x >> 16) | (v.y & 0xFFFF0000u);
        B.y = (v.z >> 16) | (v.w & 0xFFFF0000u);
        int dA = 16 * m + (cb >> 1);
        *(uint2*)&hs[row * 64 + (dA ^ swz)] = A;
        *(uint2*)&hs[row * 64 + ((dA + 8) ^ swz)] = B;
    }
    __syncthreads();

    const int w = t >> 6, l = t & 63;
    const int cc = l & 15, kg = l >> 4;

    f32x4 acc[4][2];
#pragma unroll
    for (int rt = 0; rt < 4; ++rt) {
        acc[rt][0] = (f32x4){0.f, 0.f, 0.f, 0.f};
        acc[rt][1] = (f32x4){0.f, 0.f, 0.f, 0.f};
    }

#pragma unroll
    for (int ks = 0; ks < 4; ++ks) {
        bf16x8 a[4];
#pragma unroll
        for (int rt = 0; rt < 4; ++rt) {
            int row = rt * 16 + cc;
            int idx = row * 64 + ((ks * 16 + kg * 4) ^ ((row & 7) << 2));
            a[rt] = *(const bf16x8*)&hs[idx];
        }
#pragma unroll
        for (int ctl = 0; ctl < 2; ++ctl) {
            const bf16x8 b = *(const bf16x8*)&WoF[(((size_t)(2 * w + ctl) * 4 + ks) * 64 + l) * 4];
#pragma unroll
            for (int rt = 0; rt < 4; ++rt)
                acc[rt][ctl] = __builtin_amdgcn_mfma_f32_16x16x32_bf16(a[rt], b, acc[rt][ctl], 0, 0, 0);
        }
    }

#pragma unroll
    for (int ctl = 0; ctl < 2; ++ctl) {
        int col = (2 * w + ctl) * 16 + cc;
        float bias = bo[col];
#pragma unroll
        for (int rt = 0; rt < 4; ++rt) {
#pragma unroll
            for (int j = 0; j < 4; ++j) {
                int row = row0 + rt * 16 + kg * 4 + j;
                if (row >= N) continue;
                out[(size_t)row * DD + col] = acc[rt][ctl][j] + bias;
            }
        }
    }
}

// ---------------------------------------------------------------------------
extern "C" void kernel_launch(void* const* d_in, const int* in_sizes, int n_in,
                              void* d_out, int out_size, void* d_ws, size_t ws_size,
                              hipStream_t stream) {
    const float* h   = (const float*)d_in[0];
    const float* c   = (const float*)d_in[1];
    const int*   src = (const int*)d_in[2];
    const int*   dst = (const int*)d_in[3];
    const float* Wq  = (const float*)d_in[4];
    const float* Wk  = (const float*)d_in[5];
    const float* Wv  = (const float*)d_in[6];
    const float* Wp1 = (const float*)d_in[7];
    const float* bp1 = (const float*)d_in[8];
    const float* Wp2 = (const float*)d_in[9];
    const float* bp2 = (const float*)d_in[10];
    const float* We1 = (const float*)d_in[11];
    const float* be1 = (const float*)d_in[12];
    const float* We2 = (const float*)d_in[13];
    const float* be2 = (const float*)d_in[14];
    const float* Wo  = (const float*)d_in[15];
    const float* bo  = (const float*)d_in[16];

    const int N = in_sizes[0] / DD;
    const int E = in_sizes[2];
    const int NR = (N + 511) >> 9;  // buckets of 512 nodes

    u32* BF    = (u32*)d_ws;                 // 152*256
    u32* WoF   = BF + 120 * 256;
    u32* QWb   = BF + 152 * 256;             // N*64
    u32* SPb   = QWb + (size_t)N * 64;       // N*128
    u32* headb = SPb + (size_t)N * 128;      // N*64
    int* offs  = (int*)(headb + (size_t)N * 64);   // NR*512+1
    int* grange = offs + ((size_t)NR * 512 + 1);   // 256
    int* bbase  = grange + 256;                    // 256
    int* ssrc   = bbase + 256;                     // E
    u32* ebuf   = (u32*)(ssrc + E);                // 256*CAP

    k_init<<<1, 256, 0, stream>>>(grange);

    compose_frags<<<152, 64, 0, stream>>>(Wq, Wk, Wv, We1, be1, Wp2, bp2, Wo, BF);

    node_mfma<<<(N + 63) / 64, 256, 0, stream>>>(h, c, Wp1, bp1, BF, QWb, SPb, N);

    p1_bucket<<<(E + 4095) / 4096, 256, 0, stream>>>(src, dst, grange, ebuf, E);
    k_scanB<<<1, 256, 0, stream>>>(grange, bbase);
    p2_local<<<NR, 256, 0, stream>>>(grange, bbase, ebuf, ssrc, offs, E);

    aggregate<<<(N * 64 + 255) / 256, 256, 0, stream>>>(offs, ssrc, SPb, QWb,
                                                        We2, be2, headb, N);

    out_mfma<<<(N + 63) / 64, 256, 0, stream>>>(headb, WoF, bo, (float*)d_out, N);
}

// Round 6
// 259.707 us; speedup vs baseline: 6.5631x; 1.0251x over previous
//
#include <hip/hip_runtime.h>
#include <math.h>

#define DD 128
#define CAP 10240
typedef unsigned int u32;
typedef __attribute__((ext_vector_type(8))) short bf16x8;
typedef __attribute__((ext_vector_type(4))) float f32x4;

__device__ __forceinline__ float4 f4zero() { return make_float4(0.f, 0.f, 0.f, 0.f); }
// round-to-nearest-even f32 -> bf16 (low 16 bits)
__device__ __forceinline__ u32 bf16rne(float f) {
    u32 u = __float_as_uint(f);
    u += 0x7FFFu + ((u >> 16) & 1u);
    return u >> 16;
}
__device__ __forceinline__ u32 pack2(float lo, float hi) {
    return bf16rne(lo) | (bf16rne(hi) << 16);
}
__device__ __forceinline__ float unlo(u32 u) { return __uint_as_float(u << 16); }
__device__ __forceinline__ float unhi(u32 u) { return __uint_as_float(u & 0xFFFF0000u); }

// ---------------------------------------------------------------------------
// Kernel 1: compose weights directly into MFMA B-fragment order (bf16).
// (unchanged — verified)
// ---------------------------------------------------------------------------
__global__ __launch_bounds__(64) void compose_frags(
    const float* __restrict__ Wq, const float* __restrict__ Wk,
    const float* __restrict__ Wv, const float* __restrict__ We1,
    const float* __restrict__ be1, const float* __restrict__ Wp2,
    const float* __restrict__ bp2, const float* __restrict__ Wo,
    u32* __restrict__ BF) {
    const int bid = blockIdx.x;
    const int l = threadIdx.x;
    const int c = l & 15;
    const int kg = l >> 4;
    float val[8];

    if (bid < 120) {
        const int ct = bid / 5, ks = bid - ct * 5;
        const int u = ct / 6, r = ct - u * 6;
        const int n = 32 * u + 16 * (r < 2 ? r : (r & 1)) + c;
#pragma unroll
        for (int j = 0; j < 8; ++j) {
            const int k = ks * 32 + kg * 8 + j;
            float v = 0.f;
            if (r < 2) {  // Q section
                if (k < 128) {
                    float a = 0.f;
                    for (int t = 0; t < 128; ++t)
                        a = fmaf(Wq[k * 128 + t], We1[t * 128 + n], a);
                    v = a;
                }
            } else if (r < 4) {  // K section
                if (k < 128) {
                    float a = 0.f;
                    for (int t = 0; t < 128; ++t)
                        a = fmaf(Wk[k * 128 + t], We1[t * 128 + n], a);
                    v = a;
                } else if (k < 131) {
                    float a = 0.f;
                    for (int t = 0; t < 128; ++t)
                        a = fmaf(Wp2[(k - 128) * 128 + t], We1[t * 128 + n], a);
                    v = a;
                } else if (k == 131) {
                    float a = be1[n];
                    for (int t = 0; t < 128; ++t)
                        a = fmaf(bp2[t], We1[t * 128 + n], a);
                    v = a;
                }
            } else {  // V section
                if (k < 128) v = Wv[k * 128 + n];
                else if (k < 131) v = Wp2[(k - 128) * 128 + n];
                else if (k == 131) v = bp2[n];
            }
            val[j] = v;
        }
    } else {  // Wo fragments
        const int b2 = bid - 120;
        const int ct = b2 >> 2, ks = b2 & 3;
        const int n = ct * 16 + c;
#pragma unroll
        for (int j = 0; j < 8; ++j) {
            const int k = ks * 32 + kg * 8 + j;
            val[j] = Wo[k * 128 + n];
        }
    }
    u32* dst = &BF[((size_t)bid * 64 + l) * 4];
    dst[0] = pack2(val[0], val[1]);
    dst[1] = pack2(val[2], val[3]);
    dst[2] = pack2(val[4], val[5]);
    dst[3] = pack2(val[6], val[7]);
}

// ---------------------------------------------------------------------------
// Kernel 2: node projections as one MFMA GEMM (unchanged — verified).
// ---------------------------------------------------------------------------
__global__ __launch_bounds__(256) void node_mfma(
    const float* __restrict__ h, const float* __restrict__ c,
    const float* __restrict__ Wp1, const float* __restrict__ bp1,
    const u32* __restrict__ BF,
    u32* __restrict__ QWb, u32* __restrict__ SPb, int N) {
    __shared__ u32 hs[64 * 96];  // 64 rows x 384 B (160 bf16 + pad), swizzled

    const int row0 = blockIdx.x * 64;
    const int t = threadIdx.x;

#pragma unroll
    for (int i = 0; i < 8; ++i) {
        int f = t + i * 256;
        int row = f >> 5;
        int cq = f & 31;
        float4 v = f4zero();
        if (row0 + row < N) v = *(const float4*)&h[(size_t)(row0 + row) * DD + cq * 4];
        int idx = row * 96 + ((cq * 2) ^ ((row & 7) << 2));
        uint2 p;
        p.x = pack2(v.x, v.y);
        p.y = pack2(v.z, v.w);
        *(uint2*)&hs[idx] = p;
    }
    if (t < 64) {
        int row = t;
        float u0 = 0.f, u1 = 0.f, u2 = 0.f;
        if (row0 + row < N) {
            const float* cr = &c[(size_t)(row0 + row) * 3];
            float c0 = cr[0], c1 = cr[1], c2 = cr[2];
            u0 = fmaxf(bp1[0] + c0 * Wp1[0] + c1 * Wp1[3] + c2 * Wp1[6], 0.f);
            u1 = fmaxf(bp1[1] + c0 * Wp1[1] + c1 * Wp1[4] + c2 * Wp1[7], 0.f);
            u2 = fmaxf(bp1[2] + c0 * Wp1[2] + c1 * Wp1[5] + c2 * Wp1[8], 0.f);
        }
        int swz = (row & 7) << 2;
        uint4 z0 = make_uint4(pack2(u0, u1), pack2(u2, 1.0f), 0u, 0u);
        uint4 zz = make_uint4(0u, 0u, 0u, 0u);
#pragma unroll
        for (int q = 0; q < 4; ++q) {
            int idx = row * 96 + 64 + ((q * 4) ^ swz);
            *(uint4*)&hs[idx] = (q == 0) ? z0 : zz;
        }
    }
    __syncthreads();

    const int w = t >> 6, l = t & 63;
    const int cc = l & 15, kg = l >> 4;

    f32x4 acc[4][6];
#pragma unroll
    for (int rt = 0; rt < 4; ++rt)
#pragma unroll
        for (int r = 0; r < 6; ++r) acc[rt][r] = (f32x4){0.f, 0.f, 0.f, 0.f};

#pragma unroll
    for (int ks = 0; ks < 5; ++ks) {
        bf16x8 a[4];
#pragma unroll
        for (int rt = 0; rt < 4; ++rt) {
            int row = rt * 16 + cc;
            int idx = row * 96 + ((ks * 16 + kg * 4) ^ ((row & 7) << 2));
            a[rt] = *(const bf16x8*)&hs[idx];
        }
#pragma unroll
        for (int r = 0; r < 6; ++r) {
            const bf16x8 b = *(const bf16x8*)&BF[(((size_t)(w * 6 + r) * 5 + ks) * 64 + l) * 4];
#pragma unroll
            for (int rt = 0; rt < 4; ++rt)
                acc[rt][r] = __builtin_amdgcn_mfma_f32_16x16x32_bf16(a[rt], b, acc[rt][r], 0, 0, 0);
        }
    }

#pragma unroll
    for (int rt = 0; rt < 4; ++rt) {
#pragma unroll
        for (int j = 0; j < 4; ++j) {
            int row = row0 + rt * 16 + kg * 4 + j;
            if (row >= N) continue;
            QWb[(size_t)row * 64 + w * 16 + cc] = pack2(acc[rt][0][j], acc[rt][1][j]);
            uint2 kv;
            kv.x = pack2(acc[rt][2][j], acc[rt][4][j]);
            kv.y = pack2(acc[rt][3][j], acc[rt][5][j]);
            *(uint2*)&SPb[(size_t)row * 128 + w * 32 + cc * 2] = kv;
        }
    }
}

// ---------------------------------------------------------------------------
// CSR build via two-pass LDS-ranked bucket sort (unchanged — verified),
// plus We2 reorder into SPb-slot order.
// ---------------------------------------------------------------------------
__global__ __launch_bounds__(256) void k_init(int* __restrict__ grange,
                                              const float* __restrict__ We2,
                                              float* __restrict__ We2r) {
    int t = threadIdx.x;
    grange[t] = t * CAP;
    if (t < 128) {
        // slot t: w=t>>5, q=t&31, cc=q>>1, hi=q&1 -> col = 32w + 16hi + cc
        int col = 32 * (t >> 5) + 16 * (t & 1) + ((t & 31) >> 1);
        We2r[t] = We2[col];
    }
}

__global__ __launch_bounds__(256) void p1_bucket(
    const int* __restrict__ src, const int* __restrict__ dst,
    int* __restrict__ grange, u32* __restrict__ ebuf, int E) {
    __shared__ int hist[256];
    __shared__ int base[256];
    const int t = threadIdx.x;
    hist[t] = 0;
    __syncthreads();
    const int chunk = blockIdx.x * 4096;
    int bk[16], rk[16];
    u32 pv[16];
#pragma unroll
    for (int i = 0; i < 16; ++i) {
        int idx = chunk + i * 256 + t;
        bk[i] = -1;
        if (idx < E) {
            int dd = dst[idx];
            int ss = src[idx];
            bk[i] = dd >> 9;
            pv[i] = ((u32)ss << 9) | (u32)(dd & 511);
            rk[i] = atomicAdd(&hist[bk[i]], 1);
        }
    }
    __syncthreads();
    if (hist[t]) base[t] = atomicAdd(&grange[t], hist[t]);
    __syncthreads();
#pragma unroll
    for (int i = 0; i < 16; ++i) {
        if (bk[i] >= 0) ebuf[base[bk[i]] + rk[i]] = pv[i];
    }
}

__global__ __launch_bounds__(256) void k_scanB(const int* __restrict__ grange,
                                               int* __restrict__ bucket_base) {
    __shared__ int s[256];
    int t = threadIdx.x;
    int cnt = grange[t] - t * CAP;
    int orig = cnt;
    s[t] = cnt;
    __syncthreads();
    for (int off = 1; off < 256; off <<= 1) {
        int x = (t >= off) ? s[t - off] : 0;
        __syncthreads();
        s[t] += x;
        __syncthreads();
    }
    bucket_base[t] = s[t] - orig;
}

__global__ __launch_bounds__(256) void p2_local(
    const int* __restrict__ grange, const int* __restrict__ bucket_base,
    const u32* __restrict__ ebuf, int* __restrict__ ssrc,
    int* __restrict__ offs, int E) {
    __shared__ int cnt[512];
    __shared__ int cur[512];
    __shared__ int ts[256];
    const int r = blockIdx.x;
    const int t = threadIdx.x;
    const int cnt_r = grange[r] - r * CAP;
    const int base_r = bucket_base[r];
    cnt[t] = 0;
    cnt[t + 256] = 0;
    __syncthreads();
    const u32* eb = &ebuf[(size_t)r * CAP];
    for (int i = t; i < cnt_r; i += 256) atomicAdd(&cnt[eb[i] & 511], 1);
    __syncthreads();
    int v0 = cnt[2 * t], v1 = cnt[2 * t + 1];
    int pair = v0 + v1;
    ts[t] = pair;
    __syncthreads();
    for (int off = 1; off < 256; off <<= 1) {
        int x = (t >= off) ? ts[t - off] : 0;
        __syncthreads();
        ts[t] += x;
        __syncthreads();
    }
    int ex = ts[t] - pair;
    cur[2 * t] = ex;
    cur[2 * t + 1] = ex + v0;
    offs[r * 512 + 2 * t] = base_r + ex;
    offs[r * 512 + 2 * t + 1] = base_r + ex + v0;
    if (r == gridDim.x - 1 && t == 255) offs[gridDim.x * 512] = E;
    __syncthreads();
    for (int i = t; i < cnt_r; i += 256) {
        u32 e = eb[i];
        int p = atomicAdd(&cur[e & 511], 1);
        ssrc[base_r + p] = (int)(e >> 9);
    }
}

// ---------------------------------------------------------------------------
// Kernel 3: CSR aggregate, quarter-wave-per-edge.
// Wave = one dst node. Group g (16 lanes) handles edge e0+g; lane i owns
// SPb slots 8i..8i+7 (32 B). Score butterfly: 4 steps within 16 lanes.
// Cross-group combine (xor16, xor32) once per node; group 0 writes headb.
// ---------------------------------------------------------------------------
__global__ __launch_bounds__(256) void aggregate(
    const int* __restrict__ offs, const int* __restrict__ ssrc,
    const u32* __restrict__ SPb, const u32* __restrict__ QWb,
    const float* __restrict__ We2r, const float* __restrict__ be2,
    u32* __restrict__ headb, int N) {
    const int node = (blockIdx.x * 256 + threadIdx.x) >> 6;
    const int lane = threadIdx.x & 63;
    if (node >= N) return;
    const int g = lane >> 4, i = lane & 15;

    const float INVS = 0.08838834764831845f;  // 1/sqrt(128)

    // per-node setup: Q (8 cols for my slots) + reordered We2 + bias
    uint4 Qu = *(const uint4*)&QWb[(size_t)node * 64 + 4 * i];
    float q0 = unlo(Qu.x), q1 = unhi(Qu.x), q2 = unlo(Qu.y), q3 = unhi(Qu.y);
    float q4 = unlo(Qu.z), q5 = unhi(Qu.z), q6 = unlo(Qu.w), q7 = unhi(Qu.w);
    float4 wA = *(const float4*)&We2r[8 * i];
    float4 wB = *(const float4*)&We2r[8 * i + 4];
    float b2 = be2[0];

    const int beg = offs[node], end = offs[node + 1];
    float a0 = 0.f, a1 = 0.f, a2 = 0.f, a3 = 0.f;
    float a4 = 0.f, a5 = 0.f, a6 = 0.f, a7 = 0.f;
    float zacc = 0.f;

    int e = beg + g;
    int s = (e < end) ? ssrc[e] : 0;
    for (int e0 = beg; e0 < end; e0 += 4) {
        const bool act = (e0 + g) < end;
        const int scur = s;
        const int en = e0 + 4 + g;
        s = (en < end) ? ssrc[en] : 0;  // prefetch next group edge

        const u32* row = &SPb[(size_t)scur * 128 + 8 * i];
        uint4 ua = *(const uint4*)&row[0];
        uint4 ub = *(const uint4*)&row[4];

        float p;
        p = fmaxf(unlo(ua.x) - q0, 0.f) * wA.x;
        p = fmaf(fmaxf(unlo(ua.y) - q1, 0.f), wA.y, p);
        p = fmaf(fmaxf(unlo(ua.z) - q2, 0.f), wA.z, p);
        p = fmaf(fmaxf(unlo(ua.w) - q3, 0.f), wA.w, p);
        p = fmaf(fmaxf(unlo(ub.x) - q4, 0.f), wB.x, p);
        p = fmaf(fmaxf(unlo(ub.y) - q5, 0.f), wB.y, p);
        p = fmaf(fmaxf(unlo(ub.z) - q6, 0.f), wB.z, p);
        p = fmaf(fmaxf(unlo(ub.w) - q7, 0.f), wB.w, p);
#pragma unroll
        for (int off = 1; off <= 8; off <<= 1) p += __shfl_xor(p, off);

        float sc = act ? __expf(fminf(fmaxf((p + b2) * INVS, -5.f), 5.f)) : 0.f;

        a0 = fmaf(unhi(ua.x), sc, a0);
        a1 = fmaf(unhi(ua.y), sc, a1);
        a2 = fmaf(unhi(ua.z), sc, a2);
        a3 = fmaf(unhi(ua.w), sc, a3);
        a4 = fmaf(unhi(ub.x), sc, a4);
        a5 = fmaf(unhi(ub.y), sc, a5);
        a6 = fmaf(unhi(ub.z), sc, a6);
        a7 = fmaf(unhi(ub.w), sc, a7);
        zacc += sc;
    }

    // cross-group combine
    a0 += __shfl_xor(a0, 16); a0 += __shfl_xor(a0, 32);
    a1 += __shfl_xor(a1, 16); a1 += __shfl_xor(a1, 32);
    a2 += __shfl_xor(a2, 16); a2 += __shfl_xor(a2, 32);
    a3 += __shfl_xor(a3, 16); a3 += __shfl_xor(a3, 32);
    a4 += __shfl_xor(a4, 16); a4 += __shfl_xor(a4, 32);
    a5 += __shfl_xor(a5, 16); a5 += __shfl_xor(a5, 32);
    a6 += __shfl_xor(a6, 16); a6 += __shfl_xor(a6, 32);
    a7 += __shfl_xor(a7, 16); a7 += __shfl_xor(a7, 32);
    zacc += __shfl_xor(zacc, 16); zacc += __shfl_xor(zacc, 32);

    if (g == 0) {
        float rz = 1.0f / zacc;
        uint4 o;
        o.x = pack2(a0 * rz, a1 * rz);
        o.y = pack2(a2 * rz, a3 * rz);
        o.z = pack2(a4 * rz, a5 * rz);
        o.w = pack2(a6 * rz, a7 * rz);
        *(uint4*)&headb[(size_t)node * 64 + 4 * i] = o;
    }
}

// ---------------------------------------------------------------------------
// Kernel 4: out = head @ Wo + bo via MFMA (unchanged — verified).
// ---------------------------------------------------------------------------
__global__ __launch_bounds__(256) void out_mfma(
    const u32* __restrict__ headb, const u32* __restrict__ WoF,
    const float* __restrict__ bo, float* __restrict__ out, int N) {
    __shared__ u32 hs[64 * 64];

    const int row0 = blockIdx.x * 64;
    const int t = threadIdx.x;

#pragma unroll
    for (int i = 0; i < 4; ++i) {
        int f = t + i * 256;
        int row = f >> 4;
        int cq = f & 15;
        uint4 v = make_uint4(0u, 0u, 0u, 0u);
        if (row0 + row < N) v = *(const uint4*)&headb[(size_t)(row0 + row) * 64 + cq * 4];
        int m = cq >> 2;
        int cb = (cq & 3) * 4;
        int swz = (row & 7) << 2;
        uint2 A, B;
        A.x = (v.x & 0xFFFFu) | (v.y << 16);
        A.y = (v.z & 0xFFFFu) | (v.w << 16);
        B.x = (v.x >> 16) | (v.y & 0xFFFF0000u);
        B.y = (v.z >> 16) | (v.w & 0xFFFF0000u);
        int dA = 16 * m + (cb >> 1);
        *(uint2*)&hs[row * 64 + (dA ^ swz)] = A;
        *(uint2*)&hs[row * 64 + ((dA + 8) ^ swz)] = B;
    }
    __syncthreads();

    const int w = t >> 6, l = t & 63;
    const int cc = l & 15, kg = l >> 4;

    f32x4 acc[4][2];
#pragma unroll
    for (int rt = 0; rt < 4; ++rt) {
        acc[rt][0] = (f32x4){0.f, 0.f, 0.f, 0.f};
        acc[rt][1] = (f32x4){0.f, 0.f, 0.f, 0.f};
    }

#pragma unroll
    for (int ks = 0; ks < 4; ++ks) {
        bf16x8 a[4];
#pragma unroll
        for (int rt = 0; rt < 4; ++rt) {
            int row = rt * 16 + cc;
            int idx = row * 64 + ((ks * 16 + kg * 4) ^ ((row & 7) << 2));
            a[rt] = *(const bf16x8*)&hs[idx];
        }
#pragma unroll
        for (int ctl = 0; ctl < 2; ++ctl) {
            const bf16x8 b = *(const bf16x8*)&WoF[(((size_t)(2 * w + ctl) * 4 + ks) * 64 + l) * 4];
#pragma unroll
            for (int rt = 0; rt < 4; ++rt)
                acc[rt][ctl] = __builtin_amdgcn_mfma_f32_16x16x32_bf16(a[rt], b, acc[rt][ctl], 0, 0, 0);
        }
    }

#pragma unroll
    for (int ctl = 0; ctl < 2; ++ctl) {
        int col = (2 * w + ctl) * 16 + cc;
        float bias = bo[col];
#pragma unroll
        for (int rt = 0; rt < 4; ++rt) {
#pragma unroll
            for (int j = 0; j < 4; ++j) {
                int row = row0 + rt * 16 + kg * 4 + j;
                if (row >= N) continue;
                out[(size_t)row * DD + col] = acc[rt][ctl][j] + bias;
            }
        }
    }
}

// ---------------------------------------------------------------------------
extern "C" void kernel_launch(void* const* d_in, const int* in_sizes, int n_in,
                              void* d_out, int out_size, void* d_ws, size_t ws_size,
                              hipStream_t stream) {
    const float* h   = (const float*)d_in[0];
    const float* c   = (const float*)d_in[1];
    const int*   src = (const int*)d_in[2];
    const int*   dst = (const int*)d_in[3];
    const float* Wq  = (const float*)d_in[4];
    const float* Wk  = (const float*)d_in[5];
    const float* Wv  = (const float*)d_in[6];
    const float* Wp1 = (const float*)d_in[7];
    const float* bp1 = (const float*)d_in[8];
    const float* Wp2 = (const float*)d_in[9];
    const float* bp2 = (const float*)d_in[10];
    const float* We1 = (const float*)d_in[11];
    const float* be1 = (const float*)d_in[12];
    const float* We2 = (const float*)d_in[13];
    const float* be2 = (const float*)d_in[14];
    const float* Wo  = (const float*)d_in[15];
    const float* bo  = (const float*)d_in[16];

    const int N = in_sizes[0] / DD;
    const int E = in_sizes[2];
    const int NR = (N + 511) >> 9;  // buckets of 512 nodes

    u32* BF    = (u32*)d_ws;                 // 152*256
    u32* WoF   = BF + 120 * 256;
    u32* QWb   = BF + 152 * 256;             // N*64
    u32* SPb   = QWb + (size_t)N * 64;       // N*128
    u32* headb = SPb + (size_t)N * 128;      // N*64
    int* offs  = (int*)(headb + (size_t)N * 64);   // NR*512+1
    int* grange = offs + ((size_t)NR * 512 + 1);   // 256
    int* bbase  = grange + 256;                    // 256
    float* We2r = (float*)(bbase + 256);           // 128
    int* ssrc   = (int*)(We2r + 128);              // E
    u32* ebuf   = (u32*)(ssrc + E);                // 256*CAP

    k_init<<<1, 256, 0, stream>>>(grange, We2, We2r);

    compose_frags<<<152, 64, 0, stream>>>(Wq, Wk, Wv, We1, be1, Wp2, bp2, Wo, BF);

    node_mfma<<<(N + 63) / 64, 256, 0, stream>>>(h, c, Wp1, bp1, BF, QWb, SPb, N);

    p1_bucket<<<(E + 4095) / 4096, 256, 0, stream>>>(src, dst, grange, ebuf, E);
    k_scanB<<<1, 256, 0, stream>>>(grange, bbase);
    p2_local<<<NR, 256, 0, stream>>>(grange, bbase, ebuf, ssrc, offs, E);

    aggregate<<<(N * 64 + 255) / 256, 256, 0, stream>>>(offs, ssrc, SPb, QWb,
                                                        We2r, be2, headb, N);

    out_mfma<<<(N + 63) / 64, 256, 0, stream>>>(headb, WoF, bo, (float*)d_out, N);
}

// Round 7
// 210.110 us; speedup vs baseline: 8.1123x; 1.2361x over previous
//
#include <hip/hip_runtime.h>
#include <math.h>

#define DD 128
#define CAP 10240
typedef unsigned int u32;
typedef unsigned short u16;
typedef __attribute__((ext_vector_type(8))) short bf16x8;
typedef __attribute__((ext_vector_type(4))) float f32x4;
typedef __attribute__((ext_vector_type(2))) float f32x2;

__device__ __forceinline__ float4 f4zero() { return make_float4(0.f, 0.f, 0.f, 0.f); }
// round-to-nearest-even f32 -> bf16 (low 16 bits)
__device__ __forceinline__ u32 bf16rne(float f) {
    u32 u = __float_as_uint(f);
    u += 0x7FFFu + ((u >> 16) & 1u);
    return u >> 16;
}
__device__ __forceinline__ u32 pack2(float lo, float hi) {
    return bf16rne(lo) | (bf16rne(hi) << 16);
}
__device__ __forceinline__ float unlo(u32 u) { return __uint_as_float(u << 16); }
__device__ __forceinline__ float unhi(u32 u) { return __uint_as_float(u & 0xFFFF0000u); }

// ---------------------------------------------------------------------------
// Fused pre: compose_frags (blocks 0..37, 4 sub-bids each) || p1_bucket.
// Independent work — overlapped in one launch.
// ---------------------------------------------------------------------------
__global__ __launch_bounds__(256) void fused_pre(
    const float* __restrict__ Wq, const float* __restrict__ Wk,
    const float* __restrict__ Wv, const float* __restrict__ We1,
    const float* __restrict__ be1, const float* __restrict__ Wp2,
    const float* __restrict__ bp2, const float* __restrict__ Wo,
    u32* __restrict__ BF,
    const int* __restrict__ src, const int* __restrict__ dst,
    int* __restrict__ gcount, u32* __restrict__ ebuf, int E) {
    const int t = threadIdx.x;
    if (blockIdx.x < 38) {
        // ---- compose weights into MFMA B-fragment order (bf16) ----
        const int bid = blockIdx.x * 4 + (t >> 6);
        const int l = t & 63;
        const int c = l & 15;
        const int kg = l >> 4;
        float val[8];

        if (bid < 120) {
            const int ct = bid / 5, ks = bid - ct * 5;
            const int u = ct / 6, r = ct - u * 6;
            const int n = 32 * u + 16 * (r < 2 ? r : (r & 1)) + c;
#pragma unroll
            for (int j = 0; j < 8; ++j) {
                const int k = ks * 32 + kg * 8 + j;
                float v = 0.f;
                if (r < 2) {  // Q section
                    if (k < 128) {
                        float a = 0.f;
                        for (int q = 0; q < 128; ++q)
                            a = fmaf(Wq[k * 128 + q], We1[q * 128 + n], a);
                        v = a;
                    }
                } else if (r < 4) {  // K section
                    if (k < 128) {
                        float a = 0.f;
                        for (int q = 0; q < 128; ++q)
                            a = fmaf(Wk[k * 128 + q], We1[q * 128 + n], a);
                        v = a;
                    } else if (k < 131) {
                        float a = 0.f;
                        for (int q = 0; q < 128; ++q)
                            a = fmaf(Wp2[(k - 128) * 128 + q], We1[q * 128 + n], a);
                        v = a;
                    } else if (k == 131) {
                        float a = be1[n];
                        for (int q = 0; q < 128; ++q)
                            a = fmaf(bp2[q], We1[q * 128 + n], a);
                        v = a;
                    }
                } else {  // V section
                    if (k < 128) v = Wv[k * 128 + n];
                    else if (k < 131) v = Wp2[(k - 128) * 128 + n];
                    else if (k == 131) v = bp2[n];
                }
                val[j] = v;
            }
        } else {  // Wo fragments
            const int b2 = bid - 120;
            const int ct = b2 >> 2, ks = b2 & 3;
            const int n = ct * 16 + c;
#pragma unroll
            for (int j = 0; j < 8; ++j) {
                const int k = ks * 32 + kg * 8 + j;
                val[j] = Wo[k * 128 + n];
            }
        }
        u32* dp = &BF[((size_t)bid * 64 + l) * 4];
        dp[0] = pack2(val[0], val[1]);
        dp[1] = pack2(val[2], val[3]);
        dp[2] = pack2(val[4], val[5]);
        dp[3] = pack2(val[6], val[7]);
    } else {
        // ---- p1_bucket: LDS-ranked coarse bucket (dst>>9) ----
        __shared__ int hist[256];
        __shared__ int base[256];
        hist[t] = 0;
        __syncthreads();
        const int chunk = (blockIdx.x - 38) * 4096;
        int bk[16], rk[16];
        u32 pv[16];
#pragma unroll
        for (int i = 0; i < 16; ++i) {
            int idx = chunk + i * 256 + t;
            bk[i] = -1;
            if (idx < E) {
                int dd = dst[idx];
                int ss = src[idx];
                bk[i] = dd >> 9;
                pv[i] = ((u32)ss << 9) | (u32)(dd & 511);
                rk[i] = atomicAdd(&hist[bk[i]], 1);
            }
        }
        __syncthreads();
        if (hist[t]) base[t] = t * CAP + atomicAdd(&gcount[t], hist[t]);
        __syncthreads();
#pragma unroll
        for (int i = 0; i < 16; ++i) {
            if (bk[i] >= 0) ebuf[base[bk[i]] + rk[i]] = pv[i];
        }
    }
}

// ---------------------------------------------------------------------------
// scanB + We2 reorder into slot order (slot t <-> col 32(t>>5)+16(t&1)+((t&31)>>1))
// ---------------------------------------------------------------------------
__global__ __launch_bounds__(256) void scanB_we2r(
    const int* __restrict__ gcount, int* __restrict__ bucket_base,
    const float* __restrict__ We2, float* __restrict__ We2r) {
    __shared__ int s[256];
    int t = threadIdx.x;
    int orig = gcount[t];
    s[t] = orig;
    __syncthreads();
    for (int off = 1; off < 256; off <<= 1) {
        int x = (t >= off) ? s[t - off] : 0;
        __syncthreads();
        s[t] += x;
        __syncthreads();
    }
    bucket_base[t] = s[t] - orig;
    if (t < 128) {
        int col = 32 * (t >> 5) + 16 * (t & 1) + ((t & 31) >> 1);
        We2r[t] = We2[col];
    }
}

// ---------------------------------------------------------------------------
// Fused mid: p2_local (blocks 0..NR-1) || node_mfma (rest).
// node_mfma epilogue emits: QWb bf16 (unchanged), Vb bf16 pairs, Kb8 fp8.
// ---------------------------------------------------------------------------
__global__ __launch_bounds__(256) void fused_mid(
    const float* __restrict__ h, const float* __restrict__ c,
    const float* __restrict__ Wp1, const float* __restrict__ bp1,
    const u32* __restrict__ BF,
    u32* __restrict__ QWb, u32* __restrict__ Vb,
    unsigned char* __restrict__ Kb8, int N,
    const int* __restrict__ gcount, const int* __restrict__ bucket_base,
    const u32* __restrict__ ebuf, int* __restrict__ ssrc,
    int* __restrict__ offs, int E, int NR) {
    __shared__ u32 lds[64 * 96];  // 24 KB, aliased by both paths
    const int t = threadIdx.x;

    if ((int)blockIdx.x < NR) {
        // ---- p2_local: per-bucket CSR finalize ----
        int* cnt = (int*)lds;        // 512
        int* cur = cnt + 512;        // 512
        int* ts = cur + 512;         // 256
        const int r = blockIdx.x;
        const int cnt_r = gcount[r];
        const int base_r = bucket_base[r];
        cnt[t] = 0;
        cnt[t + 256] = 0;
        __syncthreads();
        const u32* eb = &ebuf[(size_t)r * CAP];
        for (int i = t; i < cnt_r; i += 256) atomicAdd(&cnt[eb[i] & 511], 1);
        __syncthreads();
        int v0 = cnt[2 * t], v1 = cnt[2 * t + 1];
        int pair = v0 + v1;
        ts[t] = pair;
        __syncthreads();
        for (int off = 1; off < 256; off <<= 1) {
            int x = (t >= off) ? ts[t - off] : 0;
            __syncthreads();
            ts[t] += x;
            __syncthreads();
        }
        int ex = ts[t] - pair;
        cur[2 * t] = ex;
        cur[2 * t + 1] = ex + v0;
        offs[r * 512 + 2 * t] = base_r + ex;
        offs[r * 512 + 2 * t + 1] = base_r + ex + v0;
        if (r == NR - 1 && t == 255) offs[NR * 512] = E;
        __syncthreads();
        for (int i = t; i < cnt_r; i += 256) {
            u32 e = eb[i];
            int p = atomicAdd(&cur[e & 511], 1);
            ssrc[base_r + p] = (int)(e >> 9);
        }
    } else {
        // ---- node_mfma: [N x 160] @ [160 x 384] bf16 MFMA GEMM ----
        u32* hs = lds;
        const int row0 = ((int)blockIdx.x - NR) * 64;

#pragma unroll
        for (int i = 0; i < 8; ++i) {
            int f = t + i * 256;
            int row = f >> 5;
            int cq = f & 31;
            float4 v = f4zero();
            if (row0 + row < N) v = *(const float4*)&h[(size_t)(row0 + row) * DD + cq * 4];
            int idx = row * 96 + ((cq * 2) ^ ((row & 7) << 2));
            uint2 p;
            p.x = pack2(v.x, v.y);
            p.y = pack2(v.z, v.w);
            *(uint2*)&hs[idx] = p;
        }
        if (t < 64) {
            int row = t;
            float u0 = 0.f, u1 = 0.f, u2 = 0.f;
            if (row0 + row < N) {
                const float* cr = &c[(size_t)(row0 + row) * 3];
                float c0 = cr[0], c1 = cr[1], c2 = cr[2];
                u0 = fmaxf(bp1[0] + c0 * Wp1[0] + c1 * Wp1[3] + c2 * Wp1[6], 0.f);
                u1 = fmaxf(bp1[1] + c0 * Wp1[1] + c1 * Wp1[4] + c2 * Wp1[7], 0.f);
                u2 = fmaxf(bp1[2] + c0 * Wp1[2] + c1 * Wp1[5] + c2 * Wp1[8], 0.f);
            }
            int swz = (row & 7) << 2;
            uint4 z0 = make_uint4(pack2(u0, u1), pack2(u2, 1.0f), 0u, 0u);
            uint4 zz = make_uint4(0u, 0u, 0u, 0u);
#pragma unroll
            for (int q = 0; q < 4; ++q) {
                int idx = row * 96 + 64 + ((q * 4) ^ swz);
                *(uint4*)&hs[idx] = (q == 0) ? z0 : zz;
            }
        }
        __syncthreads();

        const int w = t >> 6, l = t & 63;
        const int cc = l & 15, kg = l >> 4;

        f32x4 acc[4][6];
#pragma unroll
        for (int rt = 0; rt < 4; ++rt)
#pragma unroll
            for (int r = 0; r < 6; ++r) acc[rt][r] = (f32x4){0.f, 0.f, 0.f, 0.f};

#pragma unroll
        for (int ks = 0; ks < 5; ++ks) {
            bf16x8 a[4];
#pragma unroll
            for (int rt = 0; rt < 4; ++rt) {
                int row = rt * 16 + cc;
                int idx = row * 96 + ((ks * 16 + kg * 4) ^ ((row & 7) << 2));
                a[rt] = *(const bf16x8*)&hs[idx];
            }
#pragma unroll
            for (int r = 0; r < 6; ++r) {
                const bf16x8 b = *(const bf16x8*)&BF[(((size_t)(w * 6 + r) * 5 + ks) * 64 + l) * 4];
#pragma unroll
                for (int rt = 0; rt < 4; ++rt)
                    acc[rt][r] = __builtin_amdgcn_mfma_f32_16x16x32_bf16(a[rt], b, acc[rt][r], 0, 0, 0);
            }
        }

#pragma unroll
        for (int rt = 0; rt < 4; ++rt) {
#pragma unroll
            for (int j = 0; j < 4; ++j) {
                int row = row0 + rt * 16 + kg * 4 + j;
                if (row >= N) continue;
                // Q pair (bf16): slots (2*(w*16+cc), +1)
                QWb[(size_t)row * 64 + w * 16 + cc] = pack2(acc[rt][0][j], acc[rt][1][j]);
                // V pair (bf16): Vb u32 idx 16w+cc = slots (32w+2cc, +1)
                Vb[(size_t)row * 64 + w * 16 + cc] = pack2(acc[rt][4][j], acc[rt][5][j]);
                // K pair (fp8 e4m3): bytes (32w+2cc, +1)
                u32 kp = __builtin_amdgcn_cvt_pk_fp8_f32(acc[rt][2][j], acc[rt][3][j], 0u, false);
                *(u16*)&Kb8[(size_t)row * 128 + w * 32 + cc * 2] = (u16)kp;
            }
        }
    }
}

// ---------------------------------------------------------------------------
// Aggregate: quarter-wave-per-edge; fp8 K gather (8 B/lane) + bf16 V (16 B/lane).
// ---------------------------------------------------------------------------
__global__ __launch_bounds__(256) void aggregate(
    const int* __restrict__ offs, const int* __restrict__ ssrc,
    const unsigned char* __restrict__ Kb8, const u32* __restrict__ Vb,
    const u32* __restrict__ QWb, const float* __restrict__ We2r,
    const float* __restrict__ be2, u32* __restrict__ headb, int N) {
    const int node = (blockIdx.x * 256 + threadIdx.x) >> 6;
    const int lane = threadIdx.x & 63;
    if (node >= N) return;
    const int g = lane >> 4, i = lane & 15;

    const float INVS = 0.08838834764831845f;  // 1/sqrt(128)

    uint4 Qu = *(const uint4*)&QWb[(size_t)node * 64 + 4 * i];
    float q0 = unlo(Qu.x), q1 = unhi(Qu.x), q2 = unlo(Qu.y), q3 = unhi(Qu.y);
    float q4 = unlo(Qu.z), q5 = unhi(Qu.z), q6 = unlo(Qu.w), q7 = unhi(Qu.w);
    float4 wA = *(const float4*)&We2r[8 * i];
    float4 wB = *(const float4*)&We2r[8 * i + 4];
    float b2 = be2[0];

    const int beg = offs[node], end = offs[node + 1];
    float a0 = 0.f, a1 = 0.f, a2 = 0.f, a3 = 0.f;
    float a4 = 0.f, a5 = 0.f, a6 = 0.f, a7 = 0.f;
    float zacc = 0.f;

    int e = beg + g;
    int s = (e < end) ? ssrc[e] : 0;
    for (int e0 = beg; e0 < end; e0 += 4) {
        const bool act = (e0 + g) < end;
        const int scur = s;
        const int en = e0 + 4 + g;
        s = (en < end) ? ssrc[en] : 0;  // prefetch next group edge

        uint2 kk = *(const uint2*)&Kb8[(size_t)scur * 128 + 8 * i];
        uint4 va = *(const uint4*)&Vb[(size_t)scur * 64 + 4 * i];

        f32x2 f0 = __builtin_amdgcn_cvt_pk_f32_fp8(kk.x, false);
        f32x2 f1 = __builtin_amdgcn_cvt_pk_f32_fp8(kk.x, true);
        f32x2 f2 = __builtin_amdgcn_cvt_pk_f32_fp8(kk.y, false);
        f32x2 f3 = __builtin_amdgcn_cvt_pk_f32_fp8(kk.y, true);

        float p;
        p = fmaxf(f0[0] - q0, 0.f) * wA.x;
        p = fmaf(fmaxf(f0[1] - q1, 0.f), wA.y, p);
        p = fmaf(fmaxf(f1[0] - q2, 0.f), wA.z, p);
        p = fmaf(fmaxf(f1[1] - q3, 0.f), wA.w, p);
        p = fmaf(fmaxf(f2[0] - q4, 0.f), wB.x, p);
        p = fmaf(fmaxf(f2[1] - q5, 0.f), wB.y, p);
        p = fmaf(fmaxf(f3[0] - q6, 0.f), wB.z, p);
        p = fmaf(fmaxf(f3[1] - q7, 0.f), wB.w, p);
#pragma unroll
        for (int off = 1; off <= 8; off <<= 1) p += __shfl_xor(p, off);

        float sc = act ? __expf(fminf(fmaxf((p + b2) * INVS, -5.f), 5.f)) : 0.f;

        a0 = fmaf(unlo(va.x), sc, a0);
        a1 = fmaf(unhi(va.x), sc, a1);
        a2 = fmaf(unlo(va.y), sc, a2);
        a3 = fmaf(unhi(va.y), sc, a3);
        a4 = fmaf(unlo(va.z), sc, a4);
        a5 = fmaf(unhi(va.z), sc, a5);
        a6 = fmaf(unlo(va.w), sc, a6);
        a7 = fmaf(unhi(va.w), sc, a7);
        zacc += sc;
    }

    a0 += __shfl_xor(a0, 16); a0 += __shfl_xor(a0, 32);
    a1 += __shfl_xor(a1, 16); a1 += __shfl_xor(a1, 32);
    a2 += __shfl_xor(a2, 16); a2 += __shfl_xor(a2, 32);
    a3 += __shfl_xor(a3, 16); a3 += __shfl_xor(a3, 32);
    a4 += __shfl_xor(a4, 16); a4 += __shfl_xor(a4, 32);
    a5 += __shfl_xor(a5, 16); a5 += __shfl_xor(a5, 32);
    a6 += __shfl_xor(a6, 16); a6 += __shfl_xor(a6, 32);
    a7 += __shfl_xor(a7, 16); a7 += __shfl_xor(a7, 32);
    zacc += __shfl_xor(zacc, 16); zacc += __shfl_xor(zacc, 32);

    if (g == 0) {
        float rz = 1.0f / zacc;
        uint4 o;
        o.x = pack2(a0 * rz, a1 * rz);
        o.y = pack2(a2 * rz, a3 * rz);
        o.z = pack2(a4 * rz, a5 * rz);
        o.w = pack2(a6 * rz, a7 * rz);
        *(uint4*)&headb[(size_t)node * 64 + 4 * i] = o;
    }
}

// ---------------------------------------------------------------------------
// out = head @ Wo + bo via MFMA (unchanged — verified).
// ---------------------------------------------------------------------------
__global__ __launch_bounds__(256) void out_mfma(
    const u32* __restrict__ headb, const u32* __restrict__ WoF,
    const float* __restrict__ bo, float* __restrict__ out, int N) {
    __shared__ u32 hs[64 * 64];

    const int row0 = blockIdx.x * 64;
    const int t = threadIdx.x;

#pragma unroll
    for (int i = 0; i < 4; ++i) {
        int f = t + i * 256;
        int row = f >> 4;
        int cq = f & 15;
        uint4 v = make_uint4(0u, 0u, 0u, 0u);
        if (row0 + row < N) v = *(const uint4*)&headb[(size_t)(row0 + row) * 64 + cq * 4];
        int m = cq >> 2;
        int cb = (cq & 3) * 4;
        int swz = (row & 7) << 2;
        uint2 A, B;
        A.x = (v.x & 0xFFFFu) | (v.y << 16);
        A.y = (v.z & 0xFFFFu) | (v.w << 16);
        B.x = (v.x >> 16) | (v.y & 0xFFFF0000u);
        B.y = (v.z >> 16) | (v.w & 0xFFFF0000u);
        int dA = 16 * m + (cb >> 1);
        *(uint2*)&hs[row * 64 + (dA ^ swz)] = A;
        *(uint2*)&hs[row * 64 + ((dA + 8) ^ swz)] = B;
    }
    __syncthreads();

    const int w = t >> 6, l = t & 63;
    const int cc = l & 15, kg = l >> 4;

    f32x4 acc[4][2];
#pragma unroll
    for (int rt = 0; rt < 4; ++rt) {
        acc[rt][0] = (f32x4){0.f, 0.f, 0.f, 0.f};
        acc[rt][1] = (f32x4){0.f, 0.f, 0.f, 0.f};
    }

#pragma unroll
    for (int ks = 0; ks < 4; ++ks) {
        bf16x8 a[4];
#pragma unroll
        for (int rt = 0; rt < 4; ++rt) {
            int row = rt * 16 + cc;
            int idx = row * 64 + ((ks * 16 + kg * 4) ^ ((row & 7) << 2));
            a[rt] = *(const bf16x8*)&hs[idx];
        }
#pragma unroll
        for (int ctl = 0; ctl < 2; ++ctl) {
            const bf16x8 b = *(const bf16x8*)&WoF[(((size_t)(2 * w + ctl) * 4 + ks) * 64 + l) * 4];
#pragma unroll
            for (int rt = 0; rt < 4; ++rt)
                acc[rt][ctl] = __builtin_amdgcn_mfma_f32_16x16x32_bf16(a[rt], b, acc[rt][ctl], 0, 0, 0);
        }
    }

#pragma unroll
    for (int ctl = 0; ctl < 2; ++ctl) {
        int col = (2 * w + ctl) * 16 + cc;
        float bias = bo[col];
#pragma unroll
        for (int rt = 0; rt < 4; ++rt) {
#pragma unroll
            for (int j = 0; j < 4; ++j) {
                int row = row0 + rt * 16 + kg * 4 + j;
                if (row >= N) continue;
                out[(size_t)row * DD + col] = acc[rt][ctl][j] + bias;
            }
        }
    }
}

// ---------------------------------------------------------------------------
extern "C" void kernel_launch(void* const* d_in, const int* in_sizes, int n_in,
                              void* d_out, int out_size, void* d_ws, size_t ws_size,
                              hipStream_t stream) {
    const float* h   = (const float*)d_in[0];
    const float* c   = (const float*)d_in[1];
    const int*   src = (const int*)d_in[2];
    const int*   dst = (const int*)d_in[3];
    const float* Wq  = (const float*)d_in[4];
    const float* Wk  = (const float*)d_in[5];
    const float* Wv  = (const float*)d_in[6];
    const float* Wp1 = (const float*)d_in[7];
    const float* bp1 = (const float*)d_in[8];
    const float* Wp2 = (const float*)d_in[9];
    const float* bp2 = (const float*)d_in[10];
    const float* We1 = (const float*)d_in[11];
    const float* be1 = (const float*)d_in[12];
    const float* We2 = (const float*)d_in[13];
    const float* be2 = (const float*)d_in[14];
    const float* Wo  = (const float*)d_in[15];
    const float* bo  = (const float*)d_in[16];

    const int N = in_sizes[0] / DD;
    const int E = in_sizes[2];
    const int NR = (N + 511) >> 9;  // 512-node buckets

    u32* BF    = (u32*)d_ws;                       // 152*256
    u32* WoF   = BF + 120 * 256;
    u32* QWb   = BF + 152 * 256;                   // N*64 u32
    u32* Vb    = QWb + (size_t)N * 64;             // N*64 u32
    unsigned char* Kb8 = (unsigned char*)(Vb + (size_t)N * 64);  // N*128 B
    u32* headb = (u32*)(Kb8 + (size_t)N * 128);    // N*64 u32
    int* offs  = (int*)(headb + (size_t)N * 64);   // NR*512+1
    int* gcount = offs + ((size_t)NR * 512 + 1);   // 256
    int* bbase  = gcount + 256;                    // 256
    float* We2r = (float*)(bbase + 256);           // 128
    int* ssrc   = (int*)(We2r + 128);              // E
    u32* ebuf   = (u32*)(ssrc + E);                // 256*CAP

    const int NB1 = (E + 4095) / 4096;

    hipMemsetAsync(gcount, 0, 256 * sizeof(int), stream);

    fused_pre<<<38 + NB1, 256, 0, stream>>>(Wq, Wk, Wv, We1, be1, Wp2, bp2, Wo,
                                            BF, src, dst, gcount, ebuf, E);

    scanB_we2r<<<1, 256, 0, stream>>>(gcount, bbase, We2, We2r);

    fused_mid<<<NR + (N + 63) / 64, 256, 0, stream>>>(
        h, c, Wp1, bp1, BF, QWb, Vb, Kb8, N,
        gcount, bbase, ebuf, ssrc, offs, E, NR);

    aggregate<<<(N * 64 + 255) / 256, 256, 0, stream>>>(offs, ssrc, Kb8, Vb,
                                                        QWb, We2r, be2, headb, N);

    out_mfma<<<(N + 63) / 64, 256, 0, stream>>>(headb, WoF, bo, (float*)d_out, N);
}